// Round 10
// baseline (1966.313 us; speedup 1.0000x reference)
//
#include <hip/hip_runtime.h>

#define N_NODES 100000
#define N_EDGES 3200000
#define D 64
#define G_GRAPHS 64
#define L_LAYERS 5
#define BN_EPS 1e-5f
#define RPW 8
#define NBUCK 25        // dst >> 12 buckets (4096 nodes each)
#define BSHIFT 12
#define CAPB 139264     // per-bucket capacity (mean 131072, +23 sigma)

typedef __fp16 h2 __attribute__((ext_vector_type(2)));
union h2u { unsigned u; h2 h; };

__device__ __forceinline__ unsigned pkf16(float a, float b) {
    h2u x; x.h = __builtin_amdgcn_cvt_pkrtz(a, b); return x.u;
}
__device__ __forceinline__ float dot2(unsigned a, unsigned b, float c) {
    h2u x, y; x.u = a; y.u = b;
    return __builtin_amdgcn_fdot2(x.h, y.h, c, false);
}

__device__ __forceinline__ unsigned short f2bf(float f) {  // RNE f32->bf16
    unsigned int u = __float_as_uint(f);
    u += 0x7FFFu + ((u >> 16) & 1u);
    return (unsigned short)(u >> 16);
}
__device__ __forceinline__ float bf2f(unsigned short v) {
    return __uint_as_float((unsigned int)v << 16);
}

// async global->LDS, 16B per lane; LDS dest is wave-uniform base + lane*16
__device__ __forceinline__ void gload_lds16(const void* g, void* l) {
    __builtin_amdgcn_global_load_lds(
        (const __attribute__((address_space(1))) unsigned int*)g,
        (__attribute__((address_space(3))) unsigned int*)l, 16, 0, 0);
}

__device__ __forceinline__ unsigned quant15(float a) {
    float q = fminf(fmaxf((a + 8.0f) * 2048.0f, 0.0f), 32767.0f);
    return (unsigned)__float2int_rn(q);
}

// ---------------- x -> bf16 -------------------------------------------------
__global__ __launch_bounds__(256) void xcvt_kernel(const float* __restrict__ x,
                                                   ushort* __restrict__ xbf) {
    const float4* x4 = (const float4*)x;
    ushort4* o4 = (ushort4*)xbf;
    const int total = N_NODES * D / 4;
    for (int i = blockIdx.x * blockDim.x + threadIdx.x; i < total;
         i += gridDim.x * blockDim.x) {
        float4 v = x4[i];
        ushort4 o;
        o.x = f2bf(v.x); o.y = f2bf(v.y); o.z = f2bf(v.z); o.w = f2bf(v.w);
        o4[i] = o;
    }
}

// ---------------- pass 1: bin edges by dst>>12, coalesced 256B flushes -------
// entry: x = src, y = (dst & 4095) | (attr15 << 12)
__global__ __launch_bounds__(256) void bin_kernel(const int* __restrict__ ei,
                                                  const float* __restrict__ ea,
                                                  int* __restrict__ gcur,
                                                  uint2* __restrict__ inter) {
    __shared__ uint2 ent[NBUCK][64];
    __shared__ int bcnt[NBUCK];
    __shared__ int bflu[NBUCK];
    const int tid = threadIdx.x;
    const int lane = tid & 63, wid = tid >> 6;
    if (tid < NBUCK) { bcnt[tid] = 0; bflu[tid] = 0; }
    __syncthreads();
    const int ebase = blockIdx.x * 6250;       // 512 blocks x 6250 = E exactly
    const int eend = ebase + 6250;
    for (int r = 0; r < 25; ++r) {
        int e = ebase + r * 256 + tid;
        if (e < eend) {
            int s = ei[e];
            int d = ei[N_EDGES + e];
            float a = ea[e];
            int bin = d >> BSHIFT;
            uint2 v;
            v.x = (unsigned)s;
            v.y = (unsigned)(d & 4095) | (quant15(a) << 12);
            int pos = atomicAdd(&bcnt[bin], 1);
            if (pos - bflu[bin] < 64) {
                ent[bin][pos & 63] = v;
            } else {   // rare spill: direct (correct, uncoalesced) write
                int g = atomicAdd(&gcur[bin], 1);
                inter[(size_t)bin * CAPB + g] = v;
            }
        }
        __syncthreads();
        for (int b = wid; b < NBUCK; b += 4) {
            int c = bcnt[b], f = bflu[b];
            while (c - f >= 32) {
                int g;
                if (lane == 0) g = atomicAdd(&gcur[b], 32);
                g = __shfl(g, 0);
                if (lane < 32)
                    inter[(size_t)b * CAPB + g + lane] = ent[b][(f + lane) & 63];
                f += 32;
            }
            if (lane == 0) bflu[b] = f;
        }
        __syncthreads();
    }
    // drain remainders (<32 each)
    for (int b = wid; b < NBUCK; b += 4) {
        int c = bcnt[b], f = bflu[b];
        int rem = c - f;
        if (rem > 0) {
            int g;
            if (lane == 0) g = atomicAdd(&gcur[b], rem);
            g = __shfl(g, 0);
            if (lane < rem)
                inter[(size_t)b * CAPB + g + lane] = ent[b][(f + lane) & 63];
        }
    }
}

__global__ void bscan_kernel(const int* __restrict__ gcur, int* __restrict__ bbase) {
    if (threadIdx.x == 0) {
        int s = 0;
        for (int b = 0; b < NBUCK; ++b) { bbase[b] = s; s += gcur[b]; }
    }
}

// ---------------- pass 2: per-bucket hist+scan -> row_ptr + final perm -------
// One block per bucket: its 524KB perm window stays in one XCD's L2 -> full
// dirty lines, no partial-line writeback.
__global__ __launch_bounds__(1024) void bucket_kernel(const uint2* __restrict__ inter,
                                                      const int* __restrict__ gcur,
                                                      const int* __restrict__ bbase,
                                                      unsigned* __restrict__ perm,
                                                      int* __restrict__ row_ptr) {
    __shared__ int hist[4096];
    __shared__ int part[1024];
    const int b = blockIdx.x, t = threadIdx.x;
    const int cnt = gcur[b];
    const int base = bbase[b];
    const uint2* reg = inter + (size_t)b * CAPB;
    const int n0 = b << BSHIFT;
    const int nn = min(4096, N_NODES - n0);
    #pragma unroll
    for (int k = 0; k < 4; ++k) hist[t * 4 + k] = 0;
    __syncthreads();
    for (int i = t; i < cnt; i += 1024)
        atomicAdd(&hist[reg[i].y & 4095], 1);
    __syncthreads();
    int loc[4], s = 0;
    #pragma unroll
    for (int k = 0; k < 4; ++k) { loc[k] = s; s += hist[t * 4 + k]; }
    part[t] = s;
    __syncthreads();
    for (int o = 1; o < 1024; o <<= 1) {
        int v = (t >= o) ? part[t - o] : 0;
        __syncthreads();
        part[t] += v;
        __syncthreads();
    }
    int ex = base + part[t] - s;
    #pragma unroll
    for (int k = 0; k < 4; ++k) {
        int j = t * 4 + k;
        int st = ex + loc[k];
        if (j < nn) row_ptr[n0 + j] = st;
        hist[j] = st;     // becomes absolute cursor
    }
    __syncthreads();
    for (int i = t; i < cnt; i += 1024) {
        uint2 v = reg[i];
        int p = atomicAdd(&hist[v.y & 4095], 1);
        perm[p] = (v.x << 15) | (v.y >> 12);
    }
    if (b == NBUCK - 1 && t == 0) row_ptr[N_NODES] = N_EDGES;
}

// ---------------- fused GINE layer (R9: async LDS gather + f16-dot2 GEMMs) ---
__global__ __launch_bounds__(256, 3) void layer_kernel(
    const ushort* __restrict__ hbf,      // [N][D] bf16
    const int* __restrict__ row_ptr,
    const unsigned* __restrict__ perm,
    const float* __restrict__ eps, int layer,
    const float* __restrict__ edgeW, const float* __restrict__ edgeB,
    const float* __restrict__ W1, const float* __restrict__ b1,
    const float* __restrict__ bng, const float* __restrict__ bnb,
    const float* __restrict__ W2, const float* __restrict__ b2,
    const int* __restrict__ batch,
    ushort* __restrict__ hout,           // [N][D] bf16
    float* __restrict__ pooled /* [G][D] this layer */) {
    __shared__ unsigned Wp1[32 * 64];                   // 8 KB f16x2 pairs
    __shared__ unsigned Wp2[32 * 64];                   // 8 KB
    __shared__ float bl1s[D];
    __shared__ float bl2s[D];
    __shared__ __align__(16) ushort stage[4][2][2048];  // 4 waves x 2 bufs x 4KB

    const float inv_std = rsqrtf(1.0f + BN_EPS);
    const int tid = threadIdx.x;
    for (int idx = tid; idx < 32 * 64; idx += 256) {
        int kp = idx >> 6, c = idx & 63;
        float s = bng[c] * inv_std;
        Wp1[idx] = pkf16(W1[(2 * kp) * 64 + c] * s, W1[(2 * kp + 1) * 64 + c] * s);
        Wp2[idx] = pkf16(W2[(2 * kp) * 64 + c], W2[(2 * kp + 1) * 64 + c]);
    }
    if (tid < D) {
        bl1s[tid] = fmaf(b1[tid], bng[tid] * inv_std, bnb[tid]);
        bl2s[tid] = b2[tid];
    }
    __syncthreads();

    const int lane = tid & 63;
    const int q = lane & 15;
    const int grp = lane >> 4;
    const int wid = tid >> 6;
    const int wv = blockIdx.x * 4 + wid;
    const int r0 = wv * RPW;
    if (r0 >= N_NODES) return;

    int rpv = 0;
    if (lane < 9) rpv = row_ptr[r0 + lane];
    int cval = __shfl(rpv, lane + 1) - rpv;    // degree, valid lane<8
    int bval = 0;
    if (lane < RPW) bval = batch[r0 + lane];

    const float ev = 1.0f + eps[layer];
    const float QDEC = 4.8828125e-4f;  // 1/2048
    float w4[4], b4[4], blv1[4], blv2[4];
    {
        float4 t = ((const float4*)edgeW)[q];
        w4[0] = t.x; w4[1] = t.y; w4[2] = t.z; w4[3] = t.w;
        float4 u = ((const float4*)edgeB)[q];
        b4[0] = u.x; b4[1] = u.y; b4[2] = u.z; b4[3] = u.w;
        float4 v = ((const float4*)bl1s)[q];
        blv1[0] = v.x; blv1[1] = v.y; blv1[2] = v.z; blv1[3] = v.w;
        float4 w = ((const float4*)bl2s)[q];
        blv2[0] = w.x; blv2[1] = w.y; blv2[2] = w.z; blv2[3] = w.w;
    }
    const ushort4* h4 = (const ushort4*)hbf;
    ushort4* o4 = (ushort4*)hout;

    auto nchunks = [&](int i) { return (__shfl(cval, i) + 31) >> 5; };
    int i_iss = 0, c_iss = 0;
    while (i_iss < RPW && nchunks(i_iss) == 0) ++i_iss;
    auto advance = [&]() {
        ++c_iss;
        while (i_iss < RPW) {
            if (c_iss < nchunks(i_iss)) break;
            ++i_iss; c_iss = 0;
        }
    };
    auto load_pv = [&](int i, int c) -> unsigned {
        int base = __shfl(rpv, i);
        int rem = __shfl(cval, i) - (c << 5);
        unsigned v = 0;
        if (lane < 32 && lane < rem)
            v = __builtin_nontemporal_load(perm + base + (c << 5) + lane);
        return v;
    };
    auto issue = [&](unsigned pv, int bufId) {
        ushort* sb = &stage[wid][bufId][0];
        int eloc = lane >> 3;   // edge within group of 8
        int sub = lane & 7;     // 16B chunk within row
        #pragma unroll
        for (int j = 0; j < 4; ++j) {
            unsigned pe = __shfl(pv, (j << 3) + eloc);
            gload_lds16(hbf + (size_t)(pe >> 15) * D + sub * 8, sb + j * 512);
        }
    };
    auto accumulate = [&](unsigned pv, int bufId, int ebase, int cr, float* agg) {
        const ushort* sb = &stage[wid][bufId][0];
        #pragma unroll
        for (int k = 0; k < 8; ++k) {
            int eidx = (k << 2) | grp;
            unsigned pe = __shfl(pv, eidx);
            float m = (ebase + eidx < cr) ? 1.0f : 0.0f;
            float a = fmaf((float)(pe & 0x7FFFu), QDEC, -8.0f);
            ushort4 hv = *(const ushort4*)(sb + (eidx << 6) + (q << 2));
            agg[0] = fmaf(m, fmaxf(fmaf(a, w4[0], b4[0]) + bf2f(hv.x), 0.f), agg[0]);
            agg[1] = fmaf(m, fmaxf(fmaf(a, w4[1], b4[1]) + bf2f(hv.y), 0.f), agg[1]);
            agg[2] = fmaf(m, fmaxf(fmaf(a, w4[2], b4[2]) + bf2f(hv.z), 0.f), agg[2]);
            agg[3] = fmaf(m, fmaxf(fmaf(a, w4[3], b4[3]) + bf2f(hv.w), 0.f), agg[3]);
        }
    };

    // ---- pipeline prologue: one chunk in flight ----
    bool haveNext = (i_iss < RPW);
    unsigned pvNext = haveNext ? load_pv(i_iss, c_iss) : 0u;
    unsigned pvFlight = 0;
    int bufFlight = 0, bufNext = 0;
    if (haveNext) {
        issue(pvNext, 0);
        pvFlight = pvNext;
        bufFlight = 0;
        advance();
        haveNext = (i_iss < RPW);
        pvNext = haveNext ? load_pv(i_iss, c_iss) : 0u;
        bufNext = 1;
    }

    int cur_g = -1;
    float rm[4] = {0.f, 0.f, 0.f, 0.f};
    auto flush_pool = [&]() {
        if (cur_g >= 0 && grp == 0) {
            unsigned* p = (unsigned*)&pooled[cur_g * D + 4 * q];
            atomicMax(p + 0, __float_as_uint(rm[0]));
            atomicMax(p + 1, __float_as_uint(rm[1]));
            atomicMax(p + 2, __float_as_uint(rm[2]));
            atomicMax(p + 3, __float_as_uint(rm[3]));
        }
    };
    auto pool = [&](int bg, const float* y) {
        if (bg != cur_g) {
            flush_pool();
            cur_g = bg;
            rm[0] = y[0]; rm[1] = y[1]; rm[2] = y[2]; rm[3] = y[3];
        } else {
            rm[0] = fmaxf(rm[0], y[0]); rm[1] = fmaxf(rm[1], y[1]);
            rm[2] = fmaxf(rm[2], y[2]); rm[3] = fmaxf(rm[3], y[3]);
        }
    };

    unsigned zpP0 = 0, zpP1 = 0;   // pending row's packed z

    for (int ai = 0; ai < RPW; ++ai) {
        int crA = __shfl(cval, ai);
        int nchA = (crA + 31) >> 5;
        ushort4 hs4 = h4[(size_t)(r0 + ai) * 16 + q];   // self row (prefetch)
        float agg[4] = {0.f, 0.f, 0.f, 0.f};
        for (int ac = 0; ac < nchA; ++ac) {
            unsigned pvAcc = pvFlight;
            int bufAcc = bufFlight;
            if (haveNext) {
                issue(pvNext, bufNext);
                pvFlight = pvNext;
                bufFlight = bufNext;
                advance();
                haveNext = (i_iss < RPW);
                pvNext = haveNext ? load_pv(i_iss, c_iss) : 0u;
                bufNext ^= 1;
                asm volatile("s_waitcnt vmcnt(4)" ::: "memory");
            } else {
                asm volatile("s_waitcnt vmcnt(0)" ::: "memory");
            }
            accumulate(pvAcc, bufAcc, ac << 5, crA, agg);
        }
        #pragma unroll
        for (int c = 0; c < 4; ++c) {
            agg[c] += __shfl_xor(agg[c], 16);
            agg[c] += __shfl_xor(agg[c], 32);
        }
        float z0 = fmaf(ev, bf2f(hs4.x), agg[0]);
        float z1 = fmaf(ev, bf2f(hs4.y), agg[1]);
        float z2 = fmaf(ev, bf2f(hs4.z), agg[2]);
        float z3 = fmaf(ev, bf2f(hs4.w), agg[3]);
        unsigned zc0 = pkf16(z0, z1), zc1 = pkf16(z2, z3);
        if (!(ai & 1)) {
            zpP0 = zc0; zpP1 = zc1;
            continue;
        }
        // ---- finalize row pair (r0+ai-1, r0+ai): dot2 GEMMs ----
        float pA[4] = {0,0,0,0}, pB[4] = {0,0,0,0};
        #pragma unroll
        for (int kk2 = 0; kk2 < 8; ++kk2) {
            int kp = (grp << 3) + kk2;
            int srcl = (grp << 2) + (kk2 >> 1);
            unsigned zA = __shfl((kk2 & 1) ? zpP1 : zpP0, srcl);
            unsigned zB = __shfl((kk2 & 1) ? zc1 : zc0, srcl);
            uint4 wq = *(const uint4*)&Wp1[(kp << 6) + (q << 2)];
            pA[0] = dot2(zA, wq.x, pA[0]); pA[1] = dot2(zA, wq.y, pA[1]);
            pA[2] = dot2(zA, wq.z, pA[2]); pA[3] = dot2(zA, wq.w, pA[3]);
            pB[0] = dot2(zB, wq.x, pB[0]); pB[1] = dot2(zB, wq.y, pB[1]);
            pB[2] = dot2(zB, wq.z, pB[2]); pB[3] = dot2(zB, wq.w, pB[3]);
        }
        float y1A[4], y1B[4];
        #pragma unroll
        for (int c = 0; c < 4; ++c) {
            float sA = pA[c];
            sA += __shfl_xor(sA, 16); sA += __shfl_xor(sA, 32);
            y1A[c] = fmaxf(sA + blv1[c], 0.f);
            float sB = pB[c];
            sB += __shfl_xor(sB, 16); sB += __shfl_xor(sB, 32);
            y1B[c] = fmaxf(sB + blv1[c], 0.f);
        }
        unsigned yA0 = pkf16(y1A[0], y1A[1]), yA1 = pkf16(y1A[2], y1A[3]);
        unsigned yB0 = pkf16(y1B[0], y1B[1]), yB1 = pkf16(y1B[2], y1B[3]);
        float qA[4] = {0,0,0,0}, qB[4] = {0,0,0,0};
        #pragma unroll
        for (int kk2 = 0; kk2 < 8; ++kk2) {
            int kp = (grp << 3) + kk2;
            int srcl = (grp << 2) + (kk2 >> 1);
            unsigned zA = __shfl((kk2 & 1) ? yA1 : yA0, srcl);
            unsigned zB = __shfl((kk2 & 1) ? yB1 : yB0, srcl);
            uint4 wq = *(const uint4*)&Wp2[(kp << 6) + (q << 2)];
            qA[0] = dot2(zA, wq.x, qA[0]); qA[1] = dot2(zA, wq.y, qA[1]);
            qA[2] = dot2(zA, wq.z, qA[2]); qA[3] = dot2(zA, wq.w, qA[3]);
            qB[0] = dot2(zB, wq.x, qB[0]); qB[1] = dot2(zB, wq.y, qB[1]);
            qB[2] = dot2(zB, wq.z, qB[2]); qB[3] = dot2(zB, wq.w, qB[3]);
        }
        float y2A[4], y2B[4];
        #pragma unroll
        for (int c = 0; c < 4; ++c) {
            float sA = qA[c];
            sA += __shfl_xor(sA, 16); sA += __shfl_xor(sA, 32);
            y2A[c] = fmaxf(sA + blv2[c], 0.f);
            float sB = qB[c];
            sB += __shfl_xor(sB, 16); sB += __shfl_xor(sB, 32);
            y2B[c] = fmaxf(sB + blv2[c], 0.f);
        }
        if (grp == 0) {
            ushort4 o;
            o.x = f2bf(y2A[0]); o.y = f2bf(y2A[1]);
            o.z = f2bf(y2A[2]); o.w = f2bf(y2A[3]);
            o4[(size_t)(r0 + ai - 1) * 16 + q] = o;
            ushort4 o2;
            o2.x = f2bf(y2B[0]); o2.y = f2bf(y2B[1]);
            o2.z = f2bf(y2B[2]); o2.w = f2bf(y2B[3]);
            o4[(size_t)(r0 + ai) * 16 + q] = o2;
        }
        pool(__shfl(bval, ai - 1), y2A);
        pool(__shfl(bval, ai), y2B);
    }
    flush_pool();
}

// ---------------- MLP head ---------------------------------------------------
__global__ __launch_bounds__(256) void mlp_kernel(
    const float* __restrict__ pooled,  // [5][G][D]
    const float* __restrict__ l1W, const float* __restrict__ l1b,
    const float* __restrict__ l2W, const float* __restrict__ l2b,
    float* __restrict__ out) {
    __shared__ float gl[5 * D];
    __shared__ float tl[4 * D];
    int gid = blockIdx.x;
    int tid = threadIdx.x;
    for (int idx = tid; idx < 5 * D; idx += 256) {
        int k = idx >> 6;
        int d = idx & 63;
        gl[idx] = pooled[k * (G_GRAPHS * D) + gid * D + d];
    }
    __syncthreads();
    {
        float acc = l1b[tid];
        for (int m = 0; m < 5 * D; ++m)
            acc = fmaf(gl[m], l1W[m * 256 + tid], acc);
        tl[tid] = fmaxf(acc, 0.0f);
    }
    __syncthreads();
    if (tid < 5) {
        float acc = l2b[tid];
        for (int m = 0; m < 4 * D; ++m)
            acc = fmaf(tl[m], l2W[m * 5 + tid], acc);
        out[gid * 5 + tid] = acc;
    }
}

extern "C" void kernel_launch(void* const* d_in, const int* in_sizes, int n_in,
                              void* d_out, int out_size, void* d_ws, size_t ws_size,
                              hipStream_t stream) {
    const float* x     = (const float*)d_in[0];
    const int*   ei    = (const int*)d_in[1];
    const float* ea    = (const float*)d_in[2];
    const int*   batch = (const int*)d_in[3];
    const float* eps   = (const float*)d_in[4];
    const float* edgeW = (const float*)d_in[5];
    const float* edgeB = (const float*)d_in[6];
    const float* W1    = (const float*)d_in[7];
    const float* b1    = (const float*)d_in[8];
    const float* bng   = (const float*)d_in[9];
    const float* bnb   = (const float*)d_in[10];
    const float* W2    = (const float*)d_in[11];
    const float* b2    = (const float*)d_in[12];
    const float* l1W   = (const float*)d_in[13];
    const float* l1b   = (const float*)d_in[14];
    const float* l2W   = (const float*)d_in[15];
    const float* l2b   = (const float*)d_in[16];
    float* out = (float*)d_out;

    char* ws = (char*)d_ws;
    size_t nbf = (size_t)N_NODES * D * sizeof(ushort);  // 12.8 MB
    size_t off = 0;
    ushort* hbfA  = (ushort*)(ws + off); off += nbf;
    ushort* hbfB  = (ushort*)(ws + off); off += nbf;
    float* pooled = (float*)(ws + off);  off += (size_t)L_LAYERS * G_GRAPHS * D * sizeof(float);
    off = (off + 15) & ~(size_t)15;
    unsigned* perm = (unsigned*)(ws + off); off += (size_t)N_EDGES * sizeof(unsigned); // 12.8 MB
    int* row_ptr  = (int*)(ws + off);    off += (size_t)(N_NODES + 1) * sizeof(int);
    int* gcur     = (int*)(ws + off);    off += 32 * sizeof(int);
    int* bbase    = (int*)(ws + off);    off += 32 * sizeof(int);
    off = (off + 15) & ~(size_t)15;
    uint2* inter  = (uint2*)(ws + off);  off += (size_t)NBUCK * CAPB * sizeof(uint2); // 27.9 MB

    hipMemsetAsync(gcur, 0, 32 * sizeof(int), stream);
    hipMemsetAsync(pooled, 0, (size_t)L_LAYERS * G_GRAPHS * D * sizeof(float), stream);

    xcvt_kernel<<<1024, 256, 0, stream>>>(x, hbfA);
    bin_kernel<<<512, 256, 0, stream>>>(ei, ea, gcur, inter);
    bscan_kernel<<<1, 32, 0, stream>>>(gcur, bbase);
    bucket_kernel<<<NBUCK, 1024, 0, stream>>>(inter, gcur, bbase, perm, row_ptr);

    const int waves  = (N_NODES + RPW - 1) / RPW;   // 12500
    const int blocks = (waves + 3) / 4;             // 3125

    const ushort* hcur = hbfA;
    for (int i = 0; i < L_LAYERS; ++i) {
        ushort* hnext = (i & 1) ? hbfA : hbfB;
        layer_kernel<<<blocks, 256, 0, stream>>>(
            hcur, row_ptr, perm, eps, i,
            edgeW + i * D, edgeB + i * D,
            W1 + i * D * D, b1 + i * D,
            bng + i * D, bnb + i * D,
            W2 + i * D * D, b2 + i * D,
            batch, hnext, pooled + i * G_GRAPHS * D);
        hcur = hnext;
    }
    mlp_kernel<<<G_GRAPHS, 256, 0, stream>>>(pooled, l1W, l1b, l2W, l2b, out);
}

// Round 11
// 1326.761 us; speedup vs baseline: 1.4820x; 1.4820x over previous
//
#include <hip/hip_runtime.h>

#define N_NODES 100000
#define N_EDGES 3200000
#define D 64
#define G_GRAPHS 64
#define L_LAYERS 5
#define BN_EPS 1e-5f
#define RPW 8
#define SCAN_CH 391   // 256 blocks x 391 >= 100000

typedef __fp16 h2 __attribute__((ext_vector_type(2)));
union h2u { unsigned u; h2 h; };

__device__ __forceinline__ unsigned pkf16(float a, float b) {
    h2u x; x.h = __builtin_amdgcn_cvt_pkrtz(a, b); return x.u;
}
__device__ __forceinline__ float dot2(unsigned a, unsigned b, float c) {
    h2u x, y; x.u = a; y.u = b;
    return __builtin_amdgcn_fdot2(x.h, y.h, c, false);
}

__device__ __forceinline__ unsigned short f2bf(float f) {  // RNE f32->bf16
    unsigned int u = __float_as_uint(f);
    u += 0x7FFFu + ((u >> 16) & 1u);
    return (unsigned short)(u >> 16);
}
__device__ __forceinline__ float bf2f(unsigned short v) {
    return __uint_as_float((unsigned int)v << 16);
}

// async global->LDS, 16B per lane; LDS dest is wave-uniform base + lane*16
__device__ __forceinline__ void gload_lds16(const void* g, void* l) {
    __builtin_amdgcn_global_load_lds(
        (const __attribute__((address_space(1))) unsigned int*)g,
        (__attribute__((address_space(3))) unsigned int*)l, 16, 0, 0);
}

// ---------------- x -> bf16 -------------------------------------------------
__global__ __launch_bounds__(256) void xcvt_kernel(const float* __restrict__ x,
                                                   ushort* __restrict__ xbf) {
    const float4* x4 = (const float4*)x;
    ushort4* o4 = (ushort4*)xbf;
    const int total = N_NODES * D / 4;
    for (int i = blockIdx.x * blockDim.x + threadIdx.x; i < total;
         i += gridDim.x * blockDim.x) {
        float4 v = x4[i];
        ushort4 o;
        o.x = f2bf(v.x); o.y = f2bf(v.y); o.z = f2bf(v.z); o.w = f2bf(v.w);
        o4[i] = o;
    }
}

// ---------------- dense CSR build: hist -> parallel scan -> scatter ----------
__global__ __launch_bounds__(256) void hist_kernel(const int* __restrict__ ei,
                                                   int* __restrict__ deg) {
    const int4* d4 = (const int4*)(ei + N_EDGES);
    const int n4 = N_EDGES / 4;
    for (int i = blockIdx.x * blockDim.x + threadIdx.x; i < n4;
         i += gridDim.x * blockDim.x) {
        int4 v = d4[i];
        atomicAdd(&deg[v.x], 1);
        atomicAdd(&deg[v.y], 1);
        atomicAdd(&deg[v.z], 1);
        atomicAdd(&deg[v.w], 1);
    }
}

__global__ __launch_bounds__(256) void scan_partial(const int* __restrict__ deg,
                                                    int* __restrict__ bsum) {
    __shared__ int sc[256];
    int b = blockIdx.x, t = threadIdx.x;
    int s = b * SCAN_CH, e = min(s + SCAN_CH, N_NODES);
    int sum = 0;
    for (int idx = s + t; idx < e; idx += 256) sum += deg[idx];
    sc[t] = sum;
    __syncthreads();
    for (int o = 128; o; o >>= 1) {
        if (t < o) sc[t] += sc[t + o];
        __syncthreads();
    }
    if (!t) bsum[b] = sc[0];
}

__global__ __launch_bounds__(256) void scan_base(const int* __restrict__ bsum,
                                                 int* __restrict__ bbase,
                                                 int* __restrict__ row_ptr) {
    __shared__ int sc[256];
    int t = threadIdx.x;
    int v = bsum[t];
    sc[t] = v;
    __syncthreads();
    for (int o = 1; o < 256; o <<= 1) {
        int x = (t >= o) ? sc[t - o] : 0;
        __syncthreads();
        sc[t] += x;
        __syncthreads();
    }
    bbase[t] = sc[t] - v;
    if (t == 255) row_ptr[N_NODES] = N_EDGES;
}

__global__ __launch_bounds__(256) void scan_apply(const int* __restrict__ deg,
                                                  const int* __restrict__ bbase,
                                                  int* __restrict__ row_ptr,
                                                  int* __restrict__ cursor) {
    __shared__ int sc[256];
    int b = blockIdx.x, t = threadIdx.x;
    int s = b * SCAN_CH, e = min(s + SCAN_CH, N_NODES);
    int base = bbase[b];
    for (int t0 = s; t0 < e; t0 += 256) {
        int idx = t0 + t;
        int v = (idx < e) ? deg[idx] : 0;
        sc[t] = v;
        __syncthreads();
        for (int o = 1; o < 256; o <<= 1) {
            int x = (t >= o) ? sc[t - o] : 0;
            __syncthreads();
            sc[t] += x;
            __syncthreads();
        }
        if (idx < e) {
            int ex = base + sc[t] - v;
            row_ptr[idx] = ex;
            cursor[idx] = ex;
        }
        base += sc[255];
        __syncthreads();
    }
}

// entry = (src << 15) | quant15(attr)
__device__ __forceinline__ unsigned enc_edge(int s, float a) {
    float q = fminf(fmaxf((a + 8.0f) * 2048.0f, 0.0f), 32767.0f);
    return ((unsigned)s << 15) | (unsigned)__float2int_rn(q);
}

__global__ __launch_bounds__(256) void scatter_kernel(const int* __restrict__ ei,
                                                      const float* __restrict__ ea,
                                                      int* __restrict__ cursor,
                                                      unsigned* __restrict__ perm) {
    const int4* s4 = (const int4*)ei;
    const int4* d4 = (const int4*)(ei + N_EDGES);
    const float4* a4 = (const float4*)ea;
    const int n4 = N_EDGES / 4;
    for (int i = blockIdx.x * blockDim.x + threadIdx.x; i < n4;
         i += gridDim.x * blockDim.x) {
        int4 sv = s4[i];
        int4 dv = d4[i];
        float4 av = a4[i];
        int p;
        p = atomicAdd(&cursor[dv.x], 1); __builtin_nontemporal_store(enc_edge(sv.x, av.x), perm + p);
        p = atomicAdd(&cursor[dv.y], 1); __builtin_nontemporal_store(enc_edge(sv.y, av.y), perm + p);
        p = atomicAdd(&cursor[dv.z], 1); __builtin_nontemporal_store(enc_edge(sv.z, av.z), perm + p);
        p = atomicAdd(&cursor[dv.w], 1); __builtin_nontemporal_store(enc_edge(sv.w, av.w), perm + p);
    }
}

// ---------------- fused GINE layer ------------------------------------------
// 16-edge chunks staged via global_load_lds into a 2-slot/wave LDS ring.
// LDS = 32 KB/block -> 5 blocks/CU (20 waves/CU). f16-dot2 GEMMs from LDS.
__global__ __launch_bounds__(256, 5) void layer_kernel(
    const ushort* __restrict__ hbf,      // [N][D] bf16
    const int* __restrict__ row_ptr,
    const unsigned* __restrict__ perm,
    const float* __restrict__ eps, int layer,
    const float* __restrict__ edgeW, const float* __restrict__ edgeB,
    const float* __restrict__ W1, const float* __restrict__ b1,
    const float* __restrict__ bng, const float* __restrict__ bnb,
    const float* __restrict__ W2, const float* __restrict__ b2,
    const int* __restrict__ batch,
    ushort* __restrict__ hout,           // [N][D] bf16
    float* __restrict__ pooled /* [G][D] this layer */) {
    __shared__ unsigned Wp1[32 * 64];                   // 8 KB f16x2 pairs
    __shared__ unsigned Wp2[32 * 64];                   // 8 KB
    __shared__ __align__(16) ushort stage[4][2][1024];  // 4 waves x 2 bufs x 2KB

    const float inv_std = rsqrtf(1.0f + BN_EPS);
    const int tid = threadIdx.x;
    for (int idx = tid; idx < 32 * 64; idx += 256) {
        int kp = idx >> 6, c = idx & 63;
        float s = bng[c] * inv_std;
        Wp1[idx] = pkf16(W1[(2 * kp) * 64 + c] * s, W1[(2 * kp + 1) * 64 + c] * s);
        Wp2[idx] = pkf16(W2[(2 * kp) * 64 + c], W2[(2 * kp + 1) * 64 + c]);
    }
    __syncthreads();

    const int lane = tid & 63;
    const int q = lane & 15;
    const int grp = lane >> 4;
    const int wid = tid >> 6;
    const int wv = blockIdx.x * 4 + wid;
    const int r0 = wv * RPW;          // N = 12500*8 exactly
    if (r0 >= N_NODES) return;

    int rpv = 0;
    if (lane < 9) rpv = row_ptr[r0 + lane];
    int cval = __shfl(rpv, lane + 1) - rpv;    // degree, valid lane<8
    int bval = 0;
    if (lane < RPW) bval = batch[r0 + lane];

    const float ev = 1.0f + eps[layer];
    const float QDEC = 4.8828125e-4f;  // 1/2048
    float w4[4], b4[4], blv1[4], blv2[4];
    {
        float4 t = ((const float4*)edgeW)[q];
        w4[0] = t.x; w4[1] = t.y; w4[2] = t.z; w4[3] = t.w;
        float4 u = ((const float4*)edgeB)[q];
        b4[0] = u.x; b4[1] = u.y; b4[2] = u.z; b4[3] = u.w;
        float4 g = ((const float4*)bng)[q];
        float4 v = ((const float4*)b1)[q];
        float4 bb = ((const float4*)bnb)[q];
        blv1[0] = fmaf(v.x, g.x * inv_std, bb.x);
        blv1[1] = fmaf(v.y, g.y * inv_std, bb.y);
        blv1[2] = fmaf(v.z, g.z * inv_std, bb.z);
        blv1[3] = fmaf(v.w, g.w * inv_std, bb.w);
        float4 w = ((const float4*)b2)[q];
        blv2[0] = w.x; blv2[1] = w.y; blv2[2] = w.z; blv2[3] = w.w;
    }
    const ushort4* h4 = (const ushort4*)hbf;
    ushort4* o4 = (ushort4*)hout;

    auto nchunks = [&](int i) { return (__shfl(cval, i) + 15) >> 4; };
    int i_iss = 0, c_iss = 0;
    while (i_iss < RPW && nchunks(i_iss) == 0) ++i_iss;
    auto advance = [&]() {
        ++c_iss;
        while (i_iss < RPW) {
            if (c_iss < nchunks(i_iss)) break;
            ++i_iss; c_iss = 0;
        }
    };
    auto load_pv = [&](int i, int c) -> unsigned {
        int base = __shfl(rpv, i);
        int rem = __shfl(cval, i) - (c << 4);
        unsigned v = 0;
        if (lane < 16 && lane < rem)
            v = __builtin_nontemporal_load(perm + base + (c << 4) + lane);
        return v;
    };
    auto issue = [&](unsigned pv, int bufId) {
        ushort* sb = &stage[wid][bufId][0];
        int eloc = lane >> 3;   // edge (0..7) within this instr's batch
        int sub = lane & 7;     // 16B chunk within row
        #pragma unroll
        for (int j = 0; j < 2; ++j) {
            unsigned pe = __shfl(pv, (j << 3) + eloc);
            gload_lds16(hbf + (size_t)(pe >> 15) * D + sub * 8, sb + j * 512);
        }
    };
    auto accumulate = [&](unsigned pv, int bufId, int ebase, int cr, float* agg) {
        const ushort* sb = &stage[wid][bufId][0];
        #pragma unroll
        for (int k = 0; k < 4; ++k) {
            int eidx = (k << 2) | grp;
            unsigned pe = __shfl(pv, eidx);
            float m = (ebase + eidx < cr) ? 1.0f : 0.0f;
            float a = fmaf((float)(pe & 0x7FFFu), QDEC, -8.0f);
            ushort4 hv = *(const ushort4*)(sb + (eidx << 6) + (q << 2));
            agg[0] = fmaf(m, fmaxf(fmaf(a, w4[0], b4[0]) + bf2f(hv.x), 0.f), agg[0]);
            agg[1] = fmaf(m, fmaxf(fmaf(a, w4[1], b4[1]) + bf2f(hv.y), 0.f), agg[1]);
            agg[2] = fmaf(m, fmaxf(fmaf(a, w4[2], b4[2]) + bf2f(hv.z), 0.f), agg[2]);
            agg[3] = fmaf(m, fmaxf(fmaf(a, w4[3], b4[3]) + bf2f(hv.w), 0.f), agg[3]);
        }
    };

    // ---- pipeline prologue: one chunk in flight ----
    bool haveNext = (i_iss < RPW);
    unsigned pvNext = haveNext ? load_pv(i_iss, c_iss) : 0u;
    unsigned pvFlight = 0;
    int bufFlight = 0, bufNext = 0;
    if (haveNext) {
        issue(pvNext, 0);
        pvFlight = pvNext;
        bufFlight = 0;
        advance();
        haveNext = (i_iss < RPW);
        pvNext = haveNext ? load_pv(i_iss, c_iss) : 0u;
        bufNext = 1;
    }

    int cur_g = -1;
    float rm[4] = {0.f, 0.f, 0.f, 0.f};
    auto flush_pool = [&]() {
        if (cur_g >= 0 && grp == 0) {
            unsigned* p = (unsigned*)&pooled[cur_g * D + 4 * q];
            atomicMax(p + 0, __float_as_uint(rm[0]));
            atomicMax(p + 1, __float_as_uint(rm[1]));
            atomicMax(p + 2, __float_as_uint(rm[2]));
            atomicMax(p + 3, __float_as_uint(rm[3]));
        }
    };
    auto pool = [&](int bg, const float* y) {
        if (bg != cur_g) {
            flush_pool();
            cur_g = bg;
            rm[0] = y[0]; rm[1] = y[1]; rm[2] = y[2]; rm[3] = y[3];
        } else {
            rm[0] = fmaxf(rm[0], y[0]); rm[1] = fmaxf(rm[1], y[1]);
            rm[2] = fmaxf(rm[2], y[2]); rm[3] = fmaxf(rm[3], y[3]);
        }
    };

    unsigned zpP0 = 0, zpP1 = 0;   // pending row's packed z

    for (int ai = 0; ai < RPW; ++ai) {
        int crA = __shfl(cval, ai);
        int nchA = (crA + 15) >> 4;
        ushort4 hs4 = h4[(size_t)(r0 + ai) * 16 + q];   // self row (prefetch)
        float agg[4] = {0.f, 0.f, 0.f, 0.f};
        for (int ac = 0; ac < nchA; ++ac) {
            unsigned pvAcc = pvFlight;
            int bufAcc = bufFlight;
            if (haveNext) {
                issue(pvNext, bufNext);
                pvFlight = pvNext;
                bufFlight = bufNext;
                advance();
                haveNext = (i_iss < RPW);
                pvNext = haveNext ? load_pv(i_iss, c_iss) : 0u;
                bufNext ^= 1;
                // newest 3 outstanding = next chunk's 2 gloads + its perm load
                asm volatile("s_waitcnt vmcnt(3)" ::: "memory");
            } else {
                asm volatile("s_waitcnt vmcnt(0)" ::: "memory");
            }
            accumulate(pvAcc, bufAcc, ac << 4, crA, agg);
        }
        #pragma unroll
        for (int c = 0; c < 4; ++c) {
            agg[c] += __shfl_xor(agg[c], 16);
            agg[c] += __shfl_xor(agg[c], 32);
        }
        float z0 = fmaf(ev, bf2f(hs4.x), agg[0]);
        float z1 = fmaf(ev, bf2f(hs4.y), agg[1]);
        float z2 = fmaf(ev, bf2f(hs4.z), agg[2]);
        float z3 = fmaf(ev, bf2f(hs4.w), agg[3]);
        unsigned zc0 = pkf16(z0, z1), zc1 = pkf16(z2, z3);
        if (!(ai & 1)) {
            zpP0 = zc0; zpP1 = zc1;
            continue;
        }
        // ---- finalize row pair (r0+ai-1, r0+ai): dot2 GEMMs ----
        float pA[4] = {0,0,0,0}, pB[4] = {0,0,0,0};
        #pragma unroll
        for (int kk2 = 0; kk2 < 8; ++kk2) {
            int kp = (grp << 3) + kk2;
            int srcl = (grp << 2) + (kk2 >> 1);
            unsigned zA = __shfl((kk2 & 1) ? zpP1 : zpP0, srcl);
            unsigned zB = __shfl((kk2 & 1) ? zc1 : zc0, srcl);
            uint4 wq = *(const uint4*)&Wp1[(kp << 6) + (q << 2)];
            pA[0] = dot2(zA, wq.x, pA[0]); pA[1] = dot2(zA, wq.y, pA[1]);
            pA[2] = dot2(zA, wq.z, pA[2]); pA[3] = dot2(zA, wq.w, pA[3]);
            pB[0] = dot2(zB, wq.x, pB[0]); pB[1] = dot2(zB, wq.y, pB[1]);
            pB[2] = dot2(zB, wq.z, pB[2]); pB[3] = dot2(zB, wq.w, pB[3]);
        }
        float y1A[4], y1B[4];
        #pragma unroll
        for (int c = 0; c < 4; ++c) {
            float sA = pA[c];
            sA += __shfl_xor(sA, 16); sA += __shfl_xor(sA, 32);
            y1A[c] = fmaxf(sA + blv1[c], 0.f);
            float sB = pB[c];
            sB += __shfl_xor(sB, 16); sB += __shfl_xor(sB, 32);
            y1B[c] = fmaxf(sB + blv1[c], 0.f);
        }
        unsigned yA0 = pkf16(y1A[0], y1A[1]), yA1 = pkf16(y1A[2], y1A[3]);
        unsigned yB0 = pkf16(y1B[0], y1B[1]), yB1 = pkf16(y1B[2], y1B[3]);
        float qA[4] = {0,0,0,0}, qB[4] = {0,0,0,0};
        #pragma unroll
        for (int kk2 = 0; kk2 < 8; ++kk2) {
            int kp = (grp << 3) + kk2;
            int srcl = (grp << 2) + (kk2 >> 1);
            unsigned zA = __shfl((kk2 & 1) ? yA1 : yA0, srcl);
            unsigned zB = __shfl((kk2 & 1) ? yB1 : yB0, srcl);
            uint4 wq = *(const uint4*)&Wp2[(kp << 6) + (q << 2)];
            qA[0] = dot2(zA, wq.x, qA[0]); qA[1] = dot2(zA, wq.y, qA[1]);
            qA[2] = dot2(zA, wq.z, qA[2]); qA[3] = dot2(zA, wq.w, qA[3]);
            qB[0] = dot2(zB, wq.x, qB[0]); qB[1] = dot2(zB, wq.y, qB[1]);
            qB[2] = dot2(zB, wq.z, qB[2]); qB[3] = dot2(zB, wq.w, qB[3]);
        }
        float y2A[4], y2B[4];
        #pragma unroll
        for (int c = 0; c < 4; ++c) {
            float sA = qA[c];
            sA += __shfl_xor(sA, 16); sA += __shfl_xor(sA, 32);
            y2A[c] = fmaxf(sA + blv2[c], 0.f);
            float sB = qB[c];
            sB += __shfl_xor(sB, 16); sB += __shfl_xor(sB, 32);
            y2B[c] = fmaxf(sB + blv2[c], 0.f);
        }
        if (grp == 0) {
            ushort4 o;
            o.x = f2bf(y2A[0]); o.y = f2bf(y2A[1]);
            o.z = f2bf(y2A[2]); o.w = f2bf(y2A[3]);
            o4[(size_t)(r0 + ai - 1) * 16 + q] = o;
            ushort4 o2;
            o2.x = f2bf(y2B[0]); o2.y = f2bf(y2B[1]);
            o2.z = f2bf(y2B[2]); o2.w = f2bf(y2B[3]);
            o4[(size_t)(r0 + ai) * 16 + q] = o2;
        }
        pool(__shfl(bval, ai - 1), y2A);
        pool(__shfl(bval, ai), y2B);
    }
    flush_pool();
}

// ---------------- MLP head ---------------------------------------------------
__global__ __launch_bounds__(256) void mlp_kernel(
    const float* __restrict__ pooled,  // [5][G][D]
    const float* __restrict__ l1W, const float* __restrict__ l1b,
    const float* __restrict__ l2W, const float* __restrict__ l2b,
    float* __restrict__ out) {
    __shared__ float gl[5 * D];
    __shared__ float tl[4 * D];
    int gid = blockIdx.x;
    int tid = threadIdx.x;
    for (int idx = tid; idx < 5 * D; idx += 256) {
        int k = idx >> 6;
        int d = idx & 63;
        gl[idx] = pooled[k * (G_GRAPHS * D) + gid * D + d];
    }
    __syncthreads();
    {
        float acc = l1b[tid];
        for (int m = 0; m < 5 * D; ++m)
            acc = fmaf(gl[m], l1W[m * 256 + tid], acc);
        tl[tid] = fmaxf(acc, 0.0f);
    }
    __syncthreads();
    if (tid < 5) {
        float acc = l2b[tid];
        for (int m = 0; m < 4 * D; ++m)
            acc = fmaf(tl[m], l2W[m * 5 + tid], acc);
        out[gid * 5 + tid] = acc;
    }
}

extern "C" void kernel_launch(void* const* d_in, const int* in_sizes, int n_in,
                              void* d_out, int out_size, void* d_ws, size_t ws_size,
                              hipStream_t stream) {
    const float* x     = (const float*)d_in[0];
    const int*   ei    = (const int*)d_in[1];
    const float* ea    = (const float*)d_in[2];
    const int*   batch = (const int*)d_in[3];
    const float* eps   = (const float*)d_in[4];
    const float* edgeW = (const float*)d_in[5];
    const float* edgeB = (const float*)d_in[6];
    const float* W1    = (const float*)d_in[7];
    const float* b1    = (const float*)d_in[8];
    const float* bng   = (const float*)d_in[9];
    const float* bnb   = (const float*)d_in[10];
    const float* W2    = (const float*)d_in[11];
    const float* b2    = (const float*)d_in[12];
    const float* l1W   = (const float*)d_in[13];
    const float* l1b   = (const float*)d_in[14];
    const float* l2W   = (const float*)d_in[15];
    const float* l2b   = (const float*)d_in[16];
    float* out = (float*)d_out;

    char* ws = (char*)d_ws;
    size_t nbf = (size_t)N_NODES * D * sizeof(ushort);  // 12.8 MB
    size_t off = 0;
    ushort* hbfA  = (ushort*)(ws + off); off += nbf;
    ushort* hbfB  = (ushort*)(ws + off); off += nbf;
    float* pooled = (float*)(ws + off);  off += (size_t)L_LAYERS * G_GRAPHS * D * sizeof(float);
    off = (off + 15) & ~(size_t)15;
    unsigned* perm = (unsigned*)(ws + off); off += (size_t)N_EDGES * sizeof(unsigned); // 12.8 MB
    int* deg      = (int*)(ws + off);    off += (size_t)N_NODES * sizeof(int);
    int* row_ptr  = (int*)(ws + off);    off += (size_t)(N_NODES + 1) * sizeof(int);
    int* cursor   = (int*)(ws + off);    off += (size_t)N_NODES * sizeof(int);
    int* bsum     = (int*)(ws + off);    off += 256 * sizeof(int);
    int* bbase    = (int*)(ws + off);    off += 256 * sizeof(int);

    hipMemsetAsync(deg, 0, (size_t)N_NODES * sizeof(int), stream);
    hipMemsetAsync(pooled, 0, (size_t)L_LAYERS * G_GRAPHS * D * sizeof(float), stream);

    xcvt_kernel<<<1024, 256, 0, stream>>>(x, hbfA);
    hist_kernel<<<2048, 256, 0, stream>>>(ei, deg);
    scan_partial<<<256, 256, 0, stream>>>(deg, bsum);
    scan_base<<<1, 256, 0, stream>>>(bsum, bbase, row_ptr);
    scan_apply<<<256, 256, 0, stream>>>(deg, bbase, row_ptr, cursor);
    scatter_kernel<<<2048, 256, 0, stream>>>(ei, ea, cursor, perm);

    const int waves  = (N_NODES + RPW - 1) / RPW;   // 12500
    const int blocks = (waves + 3) / 4;             // 3125

    const ushort* hcur = hbfA;
    for (int i = 0; i < L_LAYERS; ++i) {
        ushort* hnext = (i & 1) ? hbfA : hbfB;
        layer_kernel<<<blocks, 256, 0, stream>>>(
            hcur, row_ptr, perm, eps, i,
            edgeW + i * D, edgeB + i * D,
            W1 + i * D * D, b1 + i * D,
            bng + i * D, bnb + i * D,
            W2 + i * D * D, b2 + i * D,
            batch, hnext, pooled + i * G_GRAPHS * D);
        hcur = hnext;
    }
    mlp_kernel<<<G_GRAPHS, 256, 0, stream>>>(pooled, l1W, l1b, l2W, l2b, out);
}

// Round 12
// 1171.690 us; speedup vs baseline: 1.6782x; 1.1323x over previous
//
#include <hip/hip_runtime.h>

#define N_NODES 100000
#define N_EDGES 3200000
#define D 64
#define G_GRAPHS 64
#define L_LAYERS 5
#define BN_EPS 1e-5f
#define RPW 8
#define NBUCK 25      // dst>>12 buckets
#define BSHIFT 12
#define NPB 512       // partition blocks
#define EPB 6250      // edges per partition block (512*6250 = E)

typedef __fp16 h2 __attribute__((ext_vector_type(2)));
union h2u { unsigned u; h2 h; };

__device__ __forceinline__ unsigned pkf16(float a, float b) {
    h2u x; x.h = __builtin_amdgcn_cvt_pkrtz(a, b); return x.u;
}
__device__ __forceinline__ float dot2(unsigned a, unsigned b, float c) {
    h2u x, y; x.u = a; y.u = b;
    return __builtin_amdgcn_fdot2(x.h, y.h, c, false);
}

__device__ __forceinline__ unsigned short f2bf(float f) {  // RNE f32->bf16
    unsigned int u = __float_as_uint(f);
    u += 0x7FFFu + ((u >> 16) & 1u);
    return (unsigned short)(u >> 16);
}
__device__ __forceinline__ float bf2f(unsigned short v) {
    return __uint_as_float((unsigned int)v << 16);
}

// async global->LDS, 16B per lane; LDS dest is wave-uniform base + lane*16
__device__ __forceinline__ void gload_lds16(const void* g, void* l) {
    __builtin_amdgcn_global_load_lds(
        (const __attribute__((address_space(1))) unsigned int*)g,
        (__attribute__((address_space(3))) unsigned int*)l, 16, 0, 0);
}

__device__ __forceinline__ unsigned quant15(float a) {
    float q = fminf(fmaxf((a + 8.0f) * 2048.0f, 0.0f), 32767.0f);
    return (unsigned)__float2int_rn(q);
}

// ---------------- x -> bf16 -------------------------------------------------
__global__ __launch_bounds__(256) void xcvt_kernel(const float* __restrict__ x,
                                                   ushort* __restrict__ xbf) {
    const float4* x4 = (const float4*)x;
    ushort4* o4 = (ushort4*)xbf;
    const int total = N_NODES * D / 4;
    for (int i = blockIdx.x * blockDim.x + threadIdx.x; i < total;
         i += gridDim.x * blockDim.x) {
        float4 v = x4[i];
        ushort4 o;
        o.x = f2bf(v.x); o.y = f2bf(v.y); o.z = f2bf(v.z); o.w = f2bf(v.w);
        o4[i] = o;
    }
}

// ---------------- radix partition pass A: per-block bucket histogram ---------
__global__ __launch_bounds__(256) void hist512_kernel(const int* __restrict__ ei,
                                                      int* __restrict__ gcount) {
    __shared__ int cnt[NBUCK];
    const int tid = threadIdx.x, b = blockIdx.x;
    if (tid < NBUCK) cnt[tid] = 0;
    __syncthreads();
    const int ebase = b * EPB, eend = ebase + EPB;
    for (int r = 0; r < 25; ++r) {
        int e = ebase + r * 256 + tid;
        if (e < eend) atomicAdd(&cnt[ei[N_EDGES + e] >> BSHIFT], 1);
    }
    __syncthreads();
    if (tid < NBUCK) gcount[tid * NPB + b] = cnt[tid];   // bucket-major
}

// ---------------- pass B: exclusive scan of 25*512 counts --------------------
__global__ __launch_bounds__(1024) void scanp_kernel(const int* __restrict__ gcount,
                                                     int* __restrict__ ofs,
                                                     int* __restrict__ bucketbase) {
    __shared__ int part[1024];
    const int t = threadIdx.x;
    const int TOT = NBUCK * NPB;          // 12800
    const int CH = (TOT + 1023) / 1024;   // 13
    int s = t * CH, e = min(s + CH, TOT);
    int sum = 0;
    for (int i = s; i < e; ++i) sum += gcount[i];
    part[t] = sum;
    __syncthreads();
    for (int o = 1; o < 1024; o <<= 1) {
        int v = (t >= o) ? part[t - o] : 0;
        __syncthreads();
        part[t] += v;
        __syncthreads();
    }
    int base = part[t] - sum;
    for (int i = s; i < e; ++i) {
        ofs[i] = base;
        if ((i & (NPB - 1)) == 0) bucketbase[i / NPB] = base;
        base += gcount[i];
    }
    if (t == 1023) bucketbase[NBUCK] = N_EDGES;
}

// ---------------- pass C: ordered partition write (stream-contiguous) --------
// entry: x = src, y = (dst & 4095) | (attr15 << 12)
__global__ __launch_bounds__(256) void part_kernel(const int* __restrict__ ei,
                                                   const float* __restrict__ ea,
                                                   const int* __restrict__ ofs,
                                                   uint2* __restrict__ inter) {
    __shared__ int cur[NBUCK];
    const int tid = threadIdx.x, b = blockIdx.x;
    if (tid < NBUCK) cur[tid] = ofs[tid * NPB + b];
    __syncthreads();
    const int ebase = b * EPB, eend = ebase + EPB;
    for (int r = 0; r < 25; ++r) {
        int e = ebase + r * 256 + tid;
        if (e < eend) {
            int s = ei[e];
            int d = ei[N_EDGES + e];
            float a = ea[e];
            int k = d >> BSHIFT;
            int p = atomicAdd(&cur[k], 1);
            uint2 v;
            v.x = (unsigned)s;
            v.y = (unsigned)(d & 4095) | (quant15(a) << 12);
            inter[p] = v;
        }
    }
}

// ---------------- pass D: per-bucket exact sort in XCD-local L2 window -------
__global__ __launch_bounds__(1024) void bucket_kernel(const uint2* __restrict__ inter,
                                                      const int* __restrict__ bucketbase,
                                                      unsigned* __restrict__ perm,
                                                      int* __restrict__ row_ptr) {
    __shared__ int hist[4096];
    __shared__ int part[1024];
    const int b = blockIdx.x, t = threadIdx.x;
    const int beg = bucketbase[b], end = bucketbase[b + 1];
    const int cnt = end - beg;
    const uint2* reg = inter + beg;
    const int n0 = b << BSHIFT;
    const int nn = min(4096, N_NODES - n0);
    #pragma unroll
    for (int k = 0; k < 4; ++k) hist[t * 4 + k] = 0;
    __syncthreads();
    for (int i = t; i < cnt; i += 1024)
        atomicAdd(&hist[reg[i].y & 4095], 1);
    __syncthreads();
    int loc[4], s = 0;
    #pragma unroll
    for (int k = 0; k < 4; ++k) { loc[k] = s; s += hist[t * 4 + k]; }
    part[t] = s;
    __syncthreads();
    for (int o = 1; o < 1024; o <<= 1) {
        int v = (t >= o) ? part[t - o] : 0;
        __syncthreads();
        part[t] += v;
        __syncthreads();
    }
    int ex = beg + part[t] - s;
    #pragma unroll
    for (int k = 0; k < 4; ++k) {
        int j = t * 4 + k;
        int st = ex + loc[k];
        if (j < nn) row_ptr[n0 + j] = st;
        hist[j] = st;     // absolute cursor
    }
    __syncthreads();
    for (int i = t; i < cnt; i += 1024) {
        uint2 v = reg[i];
        int p = atomicAdd(&hist[v.y & 4095], 1);
        perm[p] = (v.x << 15) | (v.y >> 12);
    }
    if (b == NBUCK - 1 && t == 0) row_ptr[N_NODES] = N_EDGES;
}

// ---------------- fused GINE layer (R11, unchanged) --------------------------
__global__ __launch_bounds__(256, 5) void layer_kernel(
    const ushort* __restrict__ hbf,      // [N][D] bf16
    const int* __restrict__ row_ptr,
    const unsigned* __restrict__ perm,
    const float* __restrict__ eps, int layer,
    const float* __restrict__ edgeW, const float* __restrict__ edgeB,
    const float* __restrict__ W1, const float* __restrict__ b1,
    const float* __restrict__ bng, const float* __restrict__ bnb,
    const float* __restrict__ W2, const float* __restrict__ b2,
    const int* __restrict__ batch,
    ushort* __restrict__ hout,           // [N][D] bf16
    float* __restrict__ pooled /* [G][D] this layer */) {
    __shared__ unsigned Wp1[32 * 64];                   // 8 KB f16x2 pairs
    __shared__ unsigned Wp2[32 * 64];                   // 8 KB
    __shared__ __align__(16) ushort stage[4][2][1024];  // 4 waves x 2 bufs x 2KB

    const float inv_std = rsqrtf(1.0f + BN_EPS);
    const int tid = threadIdx.x;
    for (int idx = tid; idx < 32 * 64; idx += 256) {
        int kp = idx >> 6, c = idx & 63;
        float s = bng[c] * inv_std;
        Wp1[idx] = pkf16(W1[(2 * kp) * 64 + c] * s, W1[(2 * kp + 1) * 64 + c] * s);
        Wp2[idx] = pkf16(W2[(2 * kp) * 64 + c], W2[(2 * kp + 1) * 64 + c]);
    }
    __syncthreads();

    const int lane = tid & 63;
    const int q = lane & 15;
    const int grp = lane >> 4;
    const int wid = tid >> 6;
    const int wv = blockIdx.x * 4 + wid;
    const int r0 = wv * RPW;
    if (r0 >= N_NODES) return;

    int rpv = 0;
    if (lane < 9) rpv = row_ptr[r0 + lane];
    int cval = __shfl(rpv, lane + 1) - rpv;    // degree, valid lane<8
    int bval = 0;
    if (lane < RPW) bval = batch[r0 + lane];

    const float ev = 1.0f + eps[layer];
    const float QDEC = 4.8828125e-4f;  // 1/2048
    float w4[4], b4[4], blv1[4], blv2[4];
    {
        float4 t = ((const float4*)edgeW)[q];
        w4[0] = t.x; w4[1] = t.y; w4[2] = t.z; w4[3] = t.w;
        float4 u = ((const float4*)edgeB)[q];
        b4[0] = u.x; b4[1] = u.y; b4[2] = u.z; b4[3] = u.w;
        float4 g = ((const float4*)bng)[q];
        float4 v = ((const float4*)b1)[q];
        float4 bb = ((const float4*)bnb)[q];
        blv1[0] = fmaf(v.x, g.x * inv_std, bb.x);
        blv1[1] = fmaf(v.y, g.y * inv_std, bb.y);
        blv1[2] = fmaf(v.z, g.z * inv_std, bb.z);
        blv1[3] = fmaf(v.w, g.w * inv_std, bb.w);
        float4 w = ((const float4*)b2)[q];
        blv2[0] = w.x; blv2[1] = w.y; blv2[2] = w.z; blv2[3] = w.w;
    }
    const ushort4* h4 = (const ushort4*)hbf;
    ushort4* o4 = (ushort4*)hout;

    auto nchunks = [&](int i) { return (__shfl(cval, i) + 15) >> 4; };
    int i_iss = 0, c_iss = 0;
    while (i_iss < RPW && nchunks(i_iss) == 0) ++i_iss;
    auto advance = [&]() {
        ++c_iss;
        while (i_iss < RPW) {
            if (c_iss < nchunks(i_iss)) break;
            ++i_iss; c_iss = 0;
        }
    };
    auto load_pv = [&](int i, int c) -> unsigned {
        int base = __shfl(rpv, i);
        int rem = __shfl(cval, i) - (c << 4);
        unsigned v = 0;
        if (lane < 16 && lane < rem)
            v = __builtin_nontemporal_load(perm + base + (c << 4) + lane);
        return v;
    };
    auto issue = [&](unsigned pv, int bufId) {
        ushort* sb = &stage[wid][bufId][0];
        int eloc = lane >> 3;   // edge (0..7) within this instr's batch
        int sub = lane & 7;     // 16B chunk within row
        #pragma unroll
        for (int j = 0; j < 2; ++j) {
            unsigned pe = __shfl(pv, (j << 3) + eloc);
            gload_lds16(hbf + (size_t)(pe >> 15) * D + sub * 8, sb + j * 512);
        }
    };
    auto accumulate = [&](unsigned pv, int bufId, int ebase, int cr, float* agg) {
        const ushort* sb = &stage[wid][bufId][0];
        #pragma unroll
        for (int k = 0; k < 4; ++k) {
            int eidx = (k << 2) | grp;
            unsigned pe = __shfl(pv, eidx);
            float m = (ebase + eidx < cr) ? 1.0f : 0.0f;
            float a = fmaf((float)(pe & 0x7FFFu), QDEC, -8.0f);
            ushort4 hv = *(const ushort4*)(sb + (eidx << 6) + (q << 2));
            agg[0] = fmaf(m, fmaxf(fmaf(a, w4[0], b4[0]) + bf2f(hv.x), 0.f), agg[0]);
            agg[1] = fmaf(m, fmaxf(fmaf(a, w4[1], b4[1]) + bf2f(hv.y), 0.f), agg[1]);
            agg[2] = fmaf(m, fmaxf(fmaf(a, w4[2], b4[2]) + bf2f(hv.z), 0.f), agg[2]);
            agg[3] = fmaf(m, fmaxf(fmaf(a, w4[3], b4[3]) + bf2f(hv.w), 0.f), agg[3]);
        }
    };

    // ---- pipeline prologue: one chunk in flight ----
    bool haveNext = (i_iss < RPW);
    unsigned pvNext = haveNext ? load_pv(i_iss, c_iss) : 0u;
    unsigned pvFlight = 0;
    int bufFlight = 0, bufNext = 0;
    if (haveNext) {
        issue(pvNext, 0);
        pvFlight = pvNext;
        bufFlight = 0;
        advance();
        haveNext = (i_iss < RPW);
        pvNext = haveNext ? load_pv(i_iss, c_iss) : 0u;
        bufNext = 1;
    }

    int cur_g = -1;
    float rm[4] = {0.f, 0.f, 0.f, 0.f};
    auto flush_pool = [&]() {
        if (cur_g >= 0 && grp == 0) {
            unsigned* p = (unsigned*)&pooled[cur_g * D + 4 * q];
            atomicMax(p + 0, __float_as_uint(rm[0]));
            atomicMax(p + 1, __float_as_uint(rm[1]));
            atomicMax(p + 2, __float_as_uint(rm[2]));
            atomicMax(p + 3, __float_as_uint(rm[3]));
        }
    };
    auto pool = [&](int bg, const float* y) {
        if (bg != cur_g) {
            flush_pool();
            cur_g = bg;
            rm[0] = y[0]; rm[1] = y[1]; rm[2] = y[2]; rm[3] = y[3];
        } else {
            rm[0] = fmaxf(rm[0], y[0]); rm[1] = fmaxf(rm[1], y[1]);
            rm[2] = fmaxf(rm[2], y[2]); rm[3] = fmaxf(rm[3], y[3]);
        }
    };

    unsigned zpP0 = 0, zpP1 = 0;   // pending row's packed z

    for (int ai = 0; ai < RPW; ++ai) {
        int crA = __shfl(cval, ai);
        int nchA = (crA + 15) >> 4;
        ushort4 hs4 = h4[(size_t)(r0 + ai) * 16 + q];   // self row (prefetch)
        float agg[4] = {0.f, 0.f, 0.f, 0.f};
        for (int ac = 0; ac < nchA; ++ac) {
            unsigned pvAcc = pvFlight;
            int bufAcc = bufFlight;
            if (haveNext) {
                issue(pvNext, bufNext);
                pvFlight = pvNext;
                bufFlight = bufNext;
                advance();
                haveNext = (i_iss < RPW);
                pvNext = haveNext ? load_pv(i_iss, c_iss) : 0u;
                bufNext ^= 1;
                asm volatile("s_waitcnt vmcnt(3)" ::: "memory");
            } else {
                asm volatile("s_waitcnt vmcnt(0)" ::: "memory");
            }
            accumulate(pvAcc, bufAcc, ac << 4, crA, agg);
        }
        #pragma unroll
        for (int c = 0; c < 4; ++c) {
            agg[c] += __shfl_xor(agg[c], 16);
            agg[c] += __shfl_xor(agg[c], 32);
        }
        float z0 = fmaf(ev, bf2f(hs4.x), agg[0]);
        float z1 = fmaf(ev, bf2f(hs4.y), agg[1]);
        float z2 = fmaf(ev, bf2f(hs4.z), agg[2]);
        float z3 = fmaf(ev, bf2f(hs4.w), agg[3]);
        unsigned zc0 = pkf16(z0, z1), zc1 = pkf16(z2, z3);
        if (!(ai & 1)) {
            zpP0 = zc0; zpP1 = zc1;
            continue;
        }
        // ---- finalize row pair (r0+ai-1, r0+ai): dot2 GEMMs ----
        float pA[4] = {0,0,0,0}, pB[4] = {0,0,0,0};
        #pragma unroll
        for (int kk2 = 0; kk2 < 8; ++kk2) {
            int kp = (grp << 3) + kk2;
            int srcl = (grp << 2) + (kk2 >> 1);
            unsigned zA = __shfl((kk2 & 1) ? zpP1 : zpP0, srcl);
            unsigned zB = __shfl((kk2 & 1) ? zc1 : zc0, srcl);
            uint4 wq = *(const uint4*)&Wp1[(kp << 6) + (q << 2)];
            pA[0] = dot2(zA, wq.x, pA[0]); pA[1] = dot2(zA, wq.y, pA[1]);
            pA[2] = dot2(zA, wq.z, pA[2]); pA[3] = dot2(zA, wq.w, pA[3]);
            pB[0] = dot2(zB, wq.x, pB[0]); pB[1] = dot2(zB, wq.y, pB[1]);
            pB[2] = dot2(zB, wq.z, pB[2]); pB[3] = dot2(zB, wq.w, pB[3]);
        }
        float y1A[4], y1B[4];
        #pragma unroll
        for (int c = 0; c < 4; ++c) {
            float sA = pA[c];
            sA += __shfl_xor(sA, 16); sA += __shfl_xor(sA, 32);
            y1A[c] = fmaxf(sA + blv1[c], 0.f);
            float sB = pB[c];
            sB += __shfl_xor(sB, 16); sB += __shfl_xor(sB, 32);
            y1B[c] = fmaxf(sB + blv1[c], 0.f);
        }
        unsigned yA0 = pkf16(y1A[0], y1A[1]), yA1 = pkf16(y1A[2], y1A[3]);
        unsigned yB0 = pkf16(y1B[0], y1B[1]), yB1 = pkf16(y1B[2], y1B[3]);
        float qA[4] = {0,0,0,0}, qB[4] = {0,0,0,0};
        #pragma unroll
        for (int kk2 = 0; kk2 < 8; ++kk2) {
            int kp = (grp << 3) + kk2;
            int srcl = (grp << 2) + (kk2 >> 1);
            unsigned zA = __shfl((kk2 & 1) ? yA1 : yA0, srcl);
            unsigned zB = __shfl((kk2 & 1) ? yB1 : yB0, srcl);
            uint4 wq = *(const uint4*)&Wp2[(kp << 6) + (q << 2)];
            qA[0] = dot2(zA, wq.x, qA[0]); qA[1] = dot2(zA, wq.y, qA[1]);
            qA[2] = dot2(zA, wq.z, qA[2]); qA[3] = dot2(zA, wq.w, qA[3]);
            qB[0] = dot2(zB, wq.x, qB[0]); qB[1] = dot2(zB, wq.y, qB[1]);
            qB[2] = dot2(zB, wq.z, qB[2]); qB[3] = dot2(zB, wq.w, qB[3]);
        }
        float y2A[4], y2B[4];
        #pragma unroll
        for (int c = 0; c < 4; ++c) {
            float sA = qA[c];
            sA += __shfl_xor(sA, 16); sA += __shfl_xor(sA, 32);
            y2A[c] = fmaxf(sA + blv2[c], 0.f);
            float sB = qB[c];
            sB += __shfl_xor(sB, 16); sB += __shfl_xor(sB, 32);
            y2B[c] = fmaxf(sB + blv2[c], 0.f);
        }
        if (grp == 0) {
            ushort4 o;
            o.x = f2bf(y2A[0]); o.y = f2bf(y2A[1]);
            o.z = f2bf(y2A[2]); o.w = f2bf(y2A[3]);
            o4[(size_t)(r0 + ai - 1) * 16 + q] = o;
            ushort4 o2;
            o2.x = f2bf(y2B[0]); o2.y = f2bf(y2B[1]);
            o2.z = f2bf(y2B[2]); o2.w = f2bf(y2B[3]);
            o4[(size_t)(r0 + ai) * 16 + q] = o2;
        }
        pool(__shfl(bval, ai - 1), y2A);
        pool(__shfl(bval, ai), y2B);
    }
    flush_pool();
}

// ---------------- MLP head ---------------------------------------------------
__global__ __launch_bounds__(256) void mlp_kernel(
    const float* __restrict__ pooled,  // [5][G][D]
    const float* __restrict__ l1W, const float* __restrict__ l1b,
    const float* __restrict__ l2W, const float* __restrict__ l2b,
    float* __restrict__ out) {
    __shared__ float gl[5 * D];
    __shared__ float tl[4 * D];
    int gid = blockIdx.x;
    int tid = threadIdx.x;
    for (int idx = tid; idx < 5 * D; idx += 256) {
        int k = idx >> 6;
        int d = idx & 63;
        gl[idx] = pooled[k * (G_GRAPHS * D) + gid * D + d];
    }
    __syncthreads();
    {
        float acc = l1b[tid];
        for (int m = 0; m < 5 * D; ++m)
            acc = fmaf(gl[m], l1W[m * 256 + tid], acc);
        tl[tid] = fmaxf(acc, 0.0f);
    }
    __syncthreads();
    if (tid < 5) {
        float acc = l2b[tid];
        for (int m = 0; m < 4 * D; ++m)
            acc = fmaf(tl[m], l2W[m * 5 + tid], acc);
        out[gid * 5 + tid] = acc;
    }
}

extern "C" void kernel_launch(void* const* d_in, const int* in_sizes, int n_in,
                              void* d_out, int out_size, void* d_ws, size_t ws_size,
                              hipStream_t stream) {
    const float* x     = (const float*)d_in[0];
    const int*   ei    = (const int*)d_in[1];
    const float* ea    = (const float*)d_in[2];
    const int*   batch = (const int*)d_in[3];
    const float* eps   = (const float*)d_in[4];
    const float* edgeW = (const float*)d_in[5];
    const float* edgeB = (const float*)d_in[6];
    const float* W1    = (const float*)d_in[7];
    const float* b1    = (const float*)d_in[8];
    const float* bng   = (const float*)d_in[9];
    const float* bnb   = (const float*)d_in[10];
    const float* W2    = (const float*)d_in[11];
    const float* b2    = (const float*)d_in[12];
    const float* l1W   = (const float*)d_in[13];
    const float* l1b   = (const float*)d_in[14];
    const float* l2W   = (const float*)d_in[15];
    const float* l2b   = (const float*)d_in[16];
    float* out = (float*)d_out;

    char* ws = (char*)d_ws;
    size_t nbf = (size_t)N_NODES * D * sizeof(ushort);  // 12.8 MB
    size_t off = 0;
    ushort* hbfA  = (ushort*)(ws + off); off += nbf;
    ushort* hbfB  = (ushort*)(ws + off); off += nbf;
    float* pooled = (float*)(ws + off);  off += (size_t)L_LAYERS * G_GRAPHS * D * sizeof(float);
    off = (off + 15) & ~(size_t)15;
    unsigned* perm = (unsigned*)(ws + off); off += (size_t)N_EDGES * sizeof(unsigned); // 12.8 MB
    int* row_ptr  = (int*)(ws + off);    off += (size_t)(N_NODES + 1) * sizeof(int);
    int* gcount   = (int*)(ws + off);    off += (size_t)NBUCK * NPB * sizeof(int);
    int* ofs      = (int*)(ws + off);    off += (size_t)NBUCK * NPB * sizeof(int);
    int* bucketbase = (int*)(ws + off);  off += 32 * sizeof(int);
    off = (off + 15) & ~(size_t)15;
    uint2* inter  = (uint2*)(ws + off);  off += (size_t)N_EDGES * sizeof(uint2);  // 25.6 MB

    hipMemsetAsync(pooled, 0, (size_t)L_LAYERS * G_GRAPHS * D * sizeof(float), stream);

    xcvt_kernel<<<1024, 256, 0, stream>>>(x, hbfA);
    hist512_kernel<<<NPB, 256, 0, stream>>>(ei, gcount);
    scanp_kernel<<<1, 1024, 0, stream>>>(gcount, ofs, bucketbase);
    part_kernel<<<NPB, 256, 0, stream>>>(ei, ea, ofs, inter);
    bucket_kernel<<<NBUCK, 1024, 0, stream>>>(inter, bucketbase, perm, row_ptr);

    const int waves  = (N_NODES + RPW - 1) / RPW;   // 12500
    const int blocks = (waves + 3) / 4;             // 3125

    const ushort* hcur = hbfA;
    for (int i = 0; i < L_LAYERS; ++i) {
        ushort* hnext = (i & 1) ? hbfA : hbfB;
        layer_kernel<<<blocks, 256, 0, stream>>>(
            hcur, row_ptr, perm, eps, i,
            edgeW + i * D, edgeB + i * D,
            W1 + i * D * D, b1 + i * D,
            bng + i * D, bnb + i * D,
            W2 + i * D * D, b2 + i * D,
            batch, hnext, pooled + i * G_GRAPHS * D);
        hcur = hnext;
    }
    mlp_kernel<<<G_GRAPHS, 256, 0, stream>>>(pooled, l1W, l1b, l2W, l2b, out);
}

// Round 13
// 1100.780 us; speedup vs baseline: 1.7863x; 1.0644x over previous
//
#include <hip/hip_runtime.h>

#define N_NODES 100000
#define N_EDGES 3200000
#define D 64
#define G_GRAPHS 64
#define L_LAYERS 5
#define BN_EPS 1e-5f
#define RPW 8
#define NBUCK 25      // dst>>12 buckets
#define BSHIFT 12
#define NPB 512       // partition blocks
#define EPB 6250      // edges per partition block (512*6250 = E)

typedef __fp16 h2 __attribute__((ext_vector_type(2)));
union h2u { unsigned u; h2 h; };

__device__ __forceinline__ unsigned pkf16(float a, float b) {
    h2u x; x.h = __builtin_amdgcn_cvt_pkrtz(a, b); return x.u;
}
__device__ __forceinline__ float dot2(unsigned a, unsigned b, float c) {
    h2u x, y; x.u = a; y.u = b;
    return __builtin_amdgcn_fdot2(x.h, y.h, c, false);
}

__device__ __forceinline__ unsigned short f2bf(float f) {  // RNE f32->bf16
    unsigned int u = __float_as_uint(f);
    u += 0x7FFFu + ((u >> 16) & 1u);
    return (unsigned short)(u >> 16);
}
__device__ __forceinline__ float bf2f(unsigned short v) {
    return __uint_as_float((unsigned int)v << 16);
}

// async global->LDS, 16B per lane; LDS dest is wave-uniform base + lane*16
__device__ __forceinline__ void gload_lds16(const void* g, void* l) {
    __builtin_amdgcn_global_load_lds(
        (const __attribute__((address_space(1))) unsigned int*)g,
        (__attribute__((address_space(3))) unsigned int*)l, 16, 0, 0);
}

__device__ __forceinline__ unsigned quant15(float a) {
    float q = fminf(fmaxf((a + 8.0f) * 2048.0f, 0.0f), 32767.0f);
    return (unsigned)__float2int_rn(q);
}

// ---------------- x -> bf16 -------------------------------------------------
__global__ __launch_bounds__(256) void xcvt_kernel(const float* __restrict__ x,
                                                   ushort* __restrict__ xbf) {
    const float4* x4 = (const float4*)x;
    ushort4* o4 = (ushort4*)xbf;
    const int total = N_NODES * D / 4;
    for (int i = blockIdx.x * blockDim.x + threadIdx.x; i < total;
         i += gridDim.x * blockDim.x) {
        float4 v = x4[i];
        ushort4 o;
        o.x = f2bf(v.x); o.y = f2bf(v.y); o.z = f2bf(v.z); o.w = f2bf(v.w);
        o4[i] = o;
    }
}

// ---------------- radix partition pass A: per-block bucket histogram ---------
__global__ __launch_bounds__(256) void hist512_kernel(const int* __restrict__ ei,
                                                      int* __restrict__ gcount) {
    __shared__ int cnt[NBUCK];
    const int tid = threadIdx.x, b = blockIdx.x;
    if (tid < NBUCK) cnt[tid] = 0;
    __syncthreads();
    const int ebase = b * EPB, eend = ebase + EPB;
    for (int r = 0; r < 25; ++r) {
        int e = ebase + r * 256 + tid;
        if (e < eend) atomicAdd(&cnt[ei[N_EDGES + e] >> BSHIFT], 1);
    }
    __syncthreads();
    if (tid < NBUCK) gcount[tid * NPB + b] = cnt[tid];   // bucket-major
}

// ---------------- pass B: exclusive scan of 25*512 counts --------------------
__global__ __launch_bounds__(1024) void scanp_kernel(const int* __restrict__ gcount,
                                                     int* __restrict__ ofs,
                                                     int* __restrict__ bucketbase) {
    __shared__ int part[1024];
    const int t = threadIdx.x;
    const int TOT = NBUCK * NPB;          // 12800
    const int CH = (TOT + 1023) / 1024;   // 13
    int s = t * CH, e = min(s + CH, TOT);
    int sum = 0;
    for (int i = s; i < e; ++i) sum += gcount[i];
    part[t] = sum;
    __syncthreads();
    for (int o = 1; o < 1024; o <<= 1) {
        int v = (t >= o) ? part[t - o] : 0;
        __syncthreads();
        part[t] += v;
        __syncthreads();
    }
    int base = part[t] - sum;
    for (int i = s; i < e; ++i) {
        ofs[i] = base;
        if ((i & (NPB - 1)) == 0) bucketbase[i / NPB] = base;
        base += gcount[i];
    }
    if (t == 1023) bucketbase[NBUCK] = N_EDGES;
}

// ---------------- pass C: ordered partition write (stream-contiguous) --------
__global__ __launch_bounds__(256) void part_kernel(const int* __restrict__ ei,
                                                   const float* __restrict__ ea,
                                                   const int* __restrict__ ofs,
                                                   uint2* __restrict__ inter) {
    __shared__ int cur[NBUCK];
    const int tid = threadIdx.x, b = blockIdx.x;
    if (tid < NBUCK) cur[tid] = ofs[tid * NPB + b];
    __syncthreads();
    const int ebase = b * EPB, eend = ebase + EPB;
    for (int r = 0; r < 25; ++r) {
        int e = ebase + r * 256 + tid;
        if (e < eend) {
            int s = ei[e];
            int d = ei[N_EDGES + e];
            float a = ea[e];
            int k = d >> BSHIFT;
            int p = atomicAdd(&cur[k], 1);
            uint2 v;
            v.x = (unsigned)s;
            v.y = (unsigned)(d & 4095) | (quant15(a) << 12);
            inter[p] = v;
        }
    }
}

// ---------------- pass D: per-bucket exact sort in XCD-local L2 window -------
__global__ __launch_bounds__(1024) void bucket_kernel(const uint2* __restrict__ inter,
                                                      const int* __restrict__ bucketbase,
                                                      unsigned* __restrict__ perm,
                                                      int* __restrict__ row_ptr) {
    __shared__ int hist[4096];
    __shared__ int part[1024];
    const int b = blockIdx.x, t = threadIdx.x;
    const int beg = bucketbase[b], end = bucketbase[b + 1];
    const int cnt = end - beg;
    const uint2* reg = inter + beg;
    const int n0 = b << BSHIFT;
    const int nn = min(4096, N_NODES - n0);
    #pragma unroll
    for (int k = 0; k < 4; ++k) hist[t * 4 + k] = 0;
    __syncthreads();
    for (int i = t; i < cnt; i += 1024)
        atomicAdd(&hist[reg[i].y & 4095], 1);
    __syncthreads();
    int loc[4], s = 0;
    #pragma unroll
    for (int k = 0; k < 4; ++k) { loc[k] = s; s += hist[t * 4 + k]; }
    part[t] = s;
    __syncthreads();
    for (int o = 1; o < 1024; o <<= 1) {
        int v = (t >= o) ? part[t - o] : 0;
        __syncthreads();
        part[t] += v;
        __syncthreads();
    }
    int ex = beg + part[t] - s;
    #pragma unroll
    for (int k = 0; k < 4; ++k) {
        int j = t * 4 + k;
        int st = ex + loc[k];
        if (j < nn) row_ptr[n0 + j] = st;
        hist[j] = st;     // absolute cursor
    }
    __syncthreads();
    for (int i = t; i < cnt; i += 1024) {
        uint2 v = reg[i];
        int p = atomicAdd(&hist[v.y & 4095], 1);
        perm[p] = (v.x << 15) | (v.y >> 12);
    }
    if (b == NBUCK - 1 && t == 0) row_ptr[N_NODES] = N_EDGES;
}

// ---------------- fused GINE layer -------------------------------------------
// Perm segment staged to LDS once (pbuf) -> no per-chunk pv dependency; 3-slot
// stage ring with TRUE depth-2 gloads in flight (vmcnt 4/2/0). W2 in registers.
__global__ __launch_bounds__(256, 4) void layer_kernel(
    const ushort* __restrict__ hbf,      // [N][D] bf16
    const int* __restrict__ row_ptr,
    const unsigned* __restrict__ perm,
    const float* __restrict__ eps, int layer,
    const float* __restrict__ edgeW, const float* __restrict__ edgeB,
    const float* __restrict__ W1, const float* __restrict__ b1,
    const float* __restrict__ bng, const float* __restrict__ bnb,
    const float* __restrict__ W2, const float* __restrict__ b2,
    const int* __restrict__ batch,
    ushort* __restrict__ hout,           // [N][D] bf16
    float* __restrict__ pooled /* [G][D] this layer */) {
    __shared__ unsigned Wp1[32 * 64];                   // 8 KB f16x2 pairs
    __shared__ __align__(16) ushort stage[4][3][1024];  // 24 KB: 3-slot ring/wave
    __shared__ __align__(16) unsigned pbuf[4][512];     // 8 KB: perm segment/wave

    const float inv_std = rsqrtf(1.0f + BN_EPS);
    const int tid = threadIdx.x;
    for (int idx = tid; idx < 32 * 64; idx += 256) {
        int kp = idx >> 6, c = idx & 63;
        float s = bng[c] * inv_std;
        Wp1[idx] = pkf16(W1[(2 * kp) * 64 + c] * s, W1[(2 * kp + 1) * 64 + c] * s);
    }
    __syncthreads();

    const int lane = tid & 63;
    const int q = lane & 15;
    const int grp = lane >> 4;
    const int wid = tid >> 6;
    const int wv = blockIdx.x * 4 + wid;
    const int r0 = wv * RPW;          // N = 12500*8 exactly
    if (r0 >= N_NODES) return;

    // W2 fragments in registers: 8 x uint4 (f16x2 packed)
    uint4 w2r[8];
    #pragma unroll
    for (int kk2 = 0; kk2 < 8; ++kk2) {
        int kp = (grp << 3) + kk2;
        float4 ra = *(const float4*)&W2[(2 * kp) * 64 + (q << 2)];
        float4 rb = *(const float4*)&W2[(2 * kp + 1) * 64 + (q << 2)];
        w2r[kk2] = make_uint4(pkf16(ra.x, rb.x), pkf16(ra.y, rb.y),
                              pkf16(ra.z, rb.z), pkf16(ra.w, rb.w));
    }

    int rpv = 0;
    if (lane < 9) rpv = row_ptr[r0 + lane];
    int cval = __shfl(rpv, lane + 1) - rpv;    // degree, valid lane<8
    int bval = 0;
    if (lane < RPW) bval = batch[r0 + lane];
    const int segbase = __shfl(rpv, 0);
    const int seglen  = __shfl(rpv, 8) - segbase;

    const float ev = 1.0f + eps[layer];
    const float QDEC = 4.8828125e-4f;  // 1/2048
    float w4[4], b4[4], blv1[4], blv2[4];
    {
        float4 t = ((const float4*)edgeW)[q];
        w4[0] = t.x; w4[1] = t.y; w4[2] = t.z; w4[3] = t.w;
        float4 u = ((const float4*)edgeB)[q];
        b4[0] = u.x; b4[1] = u.y; b4[2] = u.z; b4[3] = u.w;
        float4 g = ((const float4*)bng)[q];
        float4 v = ((const float4*)b1)[q];
        float4 bb = ((const float4*)bnb)[q];
        blv1[0] = fmaf(v.x, g.x * inv_std, bb.x);
        blv1[1] = fmaf(v.y, g.y * inv_std, bb.y);
        blv1[2] = fmaf(v.z, g.z * inv_std, bb.z);
        blv1[3] = fmaf(v.w, g.w * inv_std, bb.w);
        float4 w = ((const float4*)b2)[q];
        blv2[0] = w.x; blv2[1] = w.y; blv2[2] = w.z; blv2[3] = w.w;
    }
    const ushort4* h4 = (const ushort4*)hbf;
    ushort4* o4 = (ushort4*)hout;

    // ---- pooling ----
    int cur_g = -1;
    float rm[4] = {0.f, 0.f, 0.f, 0.f};
    auto flush_pool = [&]() {
        if (cur_g >= 0 && grp == 0) {
            unsigned* p = (unsigned*)&pooled[cur_g * D + 4 * q];
            atomicMax(p + 0, __float_as_uint(rm[0]));
            atomicMax(p + 1, __float_as_uint(rm[1]));
            atomicMax(p + 2, __float_as_uint(rm[2]));
            atomicMax(p + 3, __float_as_uint(rm[3]));
        }
    };
    auto pool = [&](int bg, const float* y) {
        if (bg != cur_g) {
            flush_pool();
            cur_g = bg;
            rm[0] = y[0]; rm[1] = y[1]; rm[2] = y[2]; rm[3] = y[3];
        } else {
            rm[0] = fmaxf(rm[0], y[0]); rm[1] = fmaxf(rm[1], y[1]);
            rm[2] = fmaxf(rm[2], y[2]); rm[3] = fmaxf(rm[3], y[3]);
        }
    };

    // ---- shared row finalizer (pairs rows; GEMM1 LDS, GEMM2 regs) ----
    bool havePend = false;
    int aiPend = 0;
    unsigned zpP0 = 0, zpP1 = 0;
    auto finrow = [&](int ai, unsigned zc0, unsigned zc1) {
        if (!havePend) { zpP0 = zc0; zpP1 = zc1; aiPend = ai; havePend = true; return; }
        havePend = false;
        float pA[4] = {0,0,0,0}, pB[4] = {0,0,0,0};
        #pragma unroll
        for (int kk2 = 0; kk2 < 8; ++kk2) {
            int kp = (grp << 3) + kk2;
            int srcl = (grp << 2) + (kk2 >> 1);
            unsigned zA = __shfl((kk2 & 1) ? zpP1 : zpP0, srcl);
            unsigned zB = __shfl((kk2 & 1) ? zc1 : zc0, srcl);
            uint4 wq = *(const uint4*)&Wp1[(kp << 6) + (q << 2)];
            pA[0] = dot2(zA, wq.x, pA[0]); pA[1] = dot2(zA, wq.y, pA[1]);
            pA[2] = dot2(zA, wq.z, pA[2]); pA[3] = dot2(zA, wq.w, pA[3]);
            pB[0] = dot2(zB, wq.x, pB[0]); pB[1] = dot2(zB, wq.y, pB[1]);
            pB[2] = dot2(zB, wq.z, pB[2]); pB[3] = dot2(zB, wq.w, pB[3]);
        }
        float y1A[4], y1B[4];
        #pragma unroll
        for (int c = 0; c < 4; ++c) {
            float sA = pA[c];
            sA += __shfl_xor(sA, 16); sA += __shfl_xor(sA, 32);
            y1A[c] = fmaxf(sA + blv1[c], 0.f);
            float sB = pB[c];
            sB += __shfl_xor(sB, 16); sB += __shfl_xor(sB, 32);
            y1B[c] = fmaxf(sB + blv1[c], 0.f);
        }
        unsigned yA0 = pkf16(y1A[0], y1A[1]), yA1 = pkf16(y1A[2], y1A[3]);
        unsigned yB0 = pkf16(y1B[0], y1B[1]), yB1 = pkf16(y1B[2], y1B[3]);
        float qA[4] = {0,0,0,0}, qB[4] = {0,0,0,0};
        #pragma unroll
        for (int kk2 = 0; kk2 < 8; ++kk2) {
            int srcl = (grp << 2) + (kk2 >> 1);
            unsigned zA = __shfl((kk2 & 1) ? yA1 : yA0, srcl);
            unsigned zB = __shfl((kk2 & 1) ? yB1 : yB0, srcl);
            uint4 wq = w2r[kk2];
            qA[0] = dot2(zA, wq.x, qA[0]); qA[1] = dot2(zA, wq.y, qA[1]);
            qA[2] = dot2(zA, wq.z, qA[2]); qA[3] = dot2(zA, wq.w, qA[3]);
            qB[0] = dot2(zB, wq.x, qB[0]); qB[1] = dot2(zB, wq.y, qB[1]);
            qB[2] = dot2(zB, wq.z, qB[2]); qB[3] = dot2(zB, wq.w, qB[3]);
        }
        float y2A[4], y2B[4];
        #pragma unroll
        for (int c = 0; c < 4; ++c) {
            float sA = qA[c];
            sA += __shfl_xor(sA, 16); sA += __shfl_xor(sA, 32);
            y2A[c] = fmaxf(sA + blv2[c], 0.f);
            float sB = qB[c];
            sB += __shfl_xor(sB, 16); sB += __shfl_xor(sB, 32);
            y2B[c] = fmaxf(sB + blv2[c], 0.f);
        }
        if (grp == 0) {
            ushort4 o;
            o.x = f2bf(y2A[0]); o.y = f2bf(y2A[1]);
            o.z = f2bf(y2A[2]); o.w = f2bf(y2A[3]);
            o4[(size_t)(r0 + aiPend) * 16 + q] = o;
            ushort4 o2;
            o2.x = f2bf(y2B[0]); o2.y = f2bf(y2B[1]);
            o2.z = f2bf(y2B[2]); o2.w = f2bf(y2B[3]);
            o4[(size_t)(r0 + ai) * 16 + q] = o2;
        }
        pool(__shfl(bval, aiPend), y2A);
        pool(__shfl(bval, ai), y2B);
    };

    if (seglen <= 512) {
        // ---- fast path: perm segment in LDS, depth-2 async gather ----
        if (seglen > 0) {
            gload_lds16(perm + segbase + lane * 4, &pbuf[wid][0]);
            if (seglen > 256)
                gload_lds16(perm + segbase + 256 + lane * 4, &pbuf[wid][256]);
        }
        asm volatile("s_waitcnt vmcnt(0)" ::: "memory");  // pbuf ready

        auto nchunks = [&](int i) { return (__shfl(cval, i) + 15) >> 4; };
        int nTot = 0;
        #pragma unroll
        for (int i = 0; i < RPW; ++i) nTot += nchunks(i);

        int i_iss = 0, c_iss = 0;
        while (i_iss < RPW && nchunks(i_iss) == 0) ++i_iss;
        auto issue1 = [&](int slot) {
            int rb = __shfl(rpv, i_iss) - segbase;
            int so = rb + (c_iss << 4);
            ushort* sb = &stage[wid][slot][0];
            int eloc = lane >> 3, sub = lane & 7;
            #pragma unroll
            for (int j = 0; j < 2; ++j) {
                int idx = min(so + (j << 3) + eloc, 511);
                unsigned pe = pbuf[wid][idx];
                gload_lds16(hbf + (size_t)(pe >> 15) * D + sub * 8, sb + j * 512);
            }
            ++c_iss;
            while (i_iss < RPW) {
                if (c_iss < nchunks(i_iss)) break;
                ++i_iss; c_iss = 0;
            }
        };
        auto accumulate = [&](const ushort* sb, int rb, int ebase, int cr, float* agg) {
            #pragma unroll
            for (int k = 0; k < 4; ++k) {
                int eidx = (k << 2) | grp;
                int idx = min(rb + ebase + eidx, 511);
                unsigned pe = pbuf[wid][idx];
                float m = (ebase + eidx < cr) ? 1.0f : 0.0f;
                float a = fmaf((float)(pe & 0x7FFFu), QDEC, -8.0f);
                ushort4 hv = *(const ushort4*)(sb + (eidx << 6) + (q << 2));
                agg[0] = fmaf(m, fmaxf(fmaf(a, w4[0], b4[0]) + bf2f(hv.x), 0.f), agg[0]);
                agg[1] = fmaf(m, fmaxf(fmaf(a, w4[1], b4[1]) + bf2f(hv.y), 0.f), agg[1]);
                agg[2] = fmaf(m, fmaxf(fmaf(a, w4[2], b4[2]) + bf2f(hv.z), 0.f), agg[2]);
                agg[3] = fmaf(m, fmaxf(fmaf(a, w4[3], b4[3]) + bf2f(hv.w), 0.f), agg[3]);
            }
        };

        int nIss = 0, sIss = 0, nCon = 0, sCon = 0;
        if (nIss < nTot) { issue1(sIss); sIss = 1; ++nIss; }
        if (nIss < nTot) { issue1(sIss); sIss = 2; ++nIss; }

        for (int ai = 0; ai < RPW; ++ai) {
            int cr = __shfl(cval, ai);
            int nch = (cr + 15) >> 4;
            int rb = __shfl(rpv, ai) - segbase;
            ushort4 hs4 = h4[(size_t)(r0 + ai) * 16 + q];   // self row
            float agg[4] = {0.f, 0.f, 0.f, 0.f};
            for (int ac = 0; ac < nch; ++ac) {
                if (nIss < nTot) {
                    issue1(sIss);
                    sIss = (sIss == 2) ? 0 : sIss + 1;
                    ++nIss;
                    asm volatile("s_waitcnt vmcnt(4)" ::: "memory");
                } else if (nIss - nCon == 2) {
                    asm volatile("s_waitcnt vmcnt(2)" ::: "memory");
                } else {
                    asm volatile("s_waitcnt vmcnt(0)" ::: "memory");
                }
                accumulate(&stage[wid][sCon][0], rb, ac << 4, cr, agg);
                sCon = (sCon == 2) ? 0 : sCon + 1;
                ++nCon;
            }
            #pragma unroll
            for (int c = 0; c < 4; ++c) {
                agg[c] += __shfl_xor(agg[c], 16);
                agg[c] += __shfl_xor(agg[c], 32);
            }
            float z0 = fmaf(ev, bf2f(hs4.x), agg[0]);
            float z1 = fmaf(ev, bf2f(hs4.y), agg[1]);
            float z2 = fmaf(ev, bf2f(hs4.z), agg[2]);
            float z3 = fmaf(ev, bf2f(hs4.w), agg[3]);
            finrow(ai, pkf16(z0, z1), pkf16(z2, z3));
        }
    } else {
        // ---- rare fallback: serial direct gather (no staging) ----
        for (int ai = 0; ai < RPW; ++ai) {
            int cr = __shfl(cval, ai);
            int rbg = __shfl(rpv, ai);
            ushort4 hs4 = h4[(size_t)(r0 + ai) * 16 + q];
            float agg[4] = {0.f, 0.f, 0.f, 0.f};
            for (int k = grp; k < cr; k += 4) {
                unsigned pe = perm[rbg + k];
                float a = fmaf((float)(pe & 0x7FFFu), QDEC, -8.0f);
                ushort4 hv = h4[(size_t)(pe >> 15) * 16 + q];
                agg[0] += fmaxf(fmaf(a, w4[0], b4[0]) + bf2f(hv.x), 0.f);
                agg[1] += fmaxf(fmaf(a, w4[1], b4[1]) + bf2f(hv.y), 0.f);
                agg[2] += fmaxf(fmaf(a, w4[2], b4[2]) + bf2f(hv.z), 0.f);
                agg[3] += fmaxf(fmaf(a, w4[3], b4[3]) + bf2f(hv.w), 0.f);
            }
            #pragma unroll
            for (int c = 0; c < 4; ++c) {
                agg[c] += __shfl_xor(agg[c], 16);
                agg[c] += __shfl_xor(agg[c], 32);
            }
            float z0 = fmaf(ev, bf2f(hs4.x), agg[0]);
            float z1 = fmaf(ev, bf2f(hs4.y), agg[1]);
            float z2 = fmaf(ev, bf2f(hs4.z), agg[2]);
            float z3 = fmaf(ev, bf2f(hs4.w), agg[3]);
            finrow(ai, pkf16(z0, z1), pkf16(z2, z3));
        }
    }
    flush_pool();
}

// ---------------- MLP head ---------------------------------------------------
__global__ __launch_bounds__(256) void mlp_kernel(
    const float* __restrict__ pooled,  // [5][G][D]
    const float* __restrict__ l1W, const float* __restrict__ l1b,
    const float* __restrict__ l2W, const float* __restrict__ l2b,
    float* __restrict__ out) {
    __shared__ float gl[5 * D];
    __shared__ float tl[4 * D];
    int gid = blockIdx.x;
    int tid = threadIdx.x;
    for (int idx = tid; idx < 5 * D; idx += 256) {
        int k = idx >> 6;
        int d = idx & 63;
        gl[idx] = pooled[k * (G_GRAPHS * D) + gid * D + d];
    }
    __syncthreads();
    {
        float acc = l1b[tid];
        for (int m = 0; m < 5 * D; ++m)
            acc = fmaf(gl[m], l1W[m * 256 + tid], acc);
        tl[tid] = fmaxf(acc, 0.0f);
    }
    __syncthreads();
    if (tid < 5) {
        float acc = l2b[tid];
        for (int m = 0; m < 4 * D; ++m)
            acc = fmaf(tl[m], l2W[m * 5 + tid], acc);
        out[gid * 5 + tid] = acc;
    }
}

extern "C" void kernel_launch(void* const* d_in, const int* in_sizes, int n_in,
                              void* d_out, int out_size, void* d_ws, size_t ws_size,
                              hipStream_t stream) {
    const float* x     = (const float*)d_in[0];
    const int*   ei    = (const int*)d_in[1];
    const float* ea    = (const float*)d_in[2];
    const int*   batch = (const int*)d_in[3];
    const float* eps   = (const float*)d_in[4];
    const float* edgeW = (const float*)d_in[5];
    const float* edgeB = (const float*)d_in[6];
    const float* W1    = (const float*)d_in[7];
    const float* b1    = (const float*)d_in[8];
    const float* bng   = (const float*)d_in[9];
    const float* bnb   = (const float*)d_in[10];
    const float* W2    = (const float*)d_in[11];
    const float* b2    = (const float*)d_in[12];
    const float* l1W   = (const float*)d_in[13];
    const float* l1b   = (const float*)d_in[14];
    const float* l2W   = (const float*)d_in[15];
    const float* l2b   = (const float*)d_in[16];
    float* out = (float*)d_out;

    char* ws = (char*)d_ws;
    size_t nbf = (size_t)N_NODES * D * sizeof(ushort);  // 12.8 MB
    size_t off = 0;
    ushort* hbfA  = (ushort*)(ws + off); off += nbf;
    ushort* hbfB  = (ushort*)(ws + off); off += nbf;
    float* pooled = (float*)(ws + off);  off += (size_t)L_LAYERS * G_GRAPHS * D * sizeof(float);
    off = (off + 15) & ~(size_t)15;
    unsigned* perm = (unsigned*)(ws + off); off += (size_t)N_EDGES * sizeof(unsigned); // 12.8 MB
    int* row_ptr  = (int*)(ws + off);    off += (size_t)(N_NODES + 1) * sizeof(int);
    int* gcount   = (int*)(ws + off);    off += (size_t)NBUCK * NPB * sizeof(int);
    int* ofs      = (int*)(ws + off);    off += (size_t)NBUCK * NPB * sizeof(int);
    int* bucketbase = (int*)(ws + off);  off += 32 * sizeof(int);
    off = (off + 15) & ~(size_t)15;
    uint2* inter  = (uint2*)(ws + off);  off += (size_t)N_EDGES * sizeof(uint2);  // 25.6 MB

    hipMemsetAsync(pooled, 0, (size_t)L_LAYERS * G_GRAPHS * D * sizeof(float), stream);

    xcvt_kernel<<<1024, 256, 0, stream>>>(x, hbfA);
    hist512_kernel<<<NPB, 256, 0, stream>>>(ei, gcount);
    scanp_kernel<<<1, 1024, 0, stream>>>(gcount, ofs, bucketbase);
    part_kernel<<<NPB, 256, 0, stream>>>(ei, ea, ofs, inter);
    bucket_kernel<<<NBUCK, 1024, 0, stream>>>(inter, bucketbase, perm, row_ptr);

    const int waves  = (N_NODES + RPW - 1) / RPW;   // 12500
    const int blocks = (waves + 3) / 4;             // 3125

    const ushort* hcur = hbfA;
    for (int i = 0; i < L_LAYERS; ++i) {
        ushort* hnext = (i & 1) ? hbfA : hbfB;
        layer_kernel<<<blocks, 256, 0, stream>>>(
            hcur, row_ptr, perm, eps, i,
            edgeW + i * D, edgeB + i * D,
            W1 + i * D * D, b1 + i * D,
            bng + i * D, bnb + i * D,
            W2 + i * D * D, b2 + i * D,
            batch, hnext, pooled + i * G_GRAPHS * D);
        hcur = hnext;
    }
    mlp_kernel<<<G_GRAPHS, 256, 0, stream>>>(pooled, l1W, l1b, l2W, l2b, out);
}

// Round 14
// 957.530 us; speedup vs baseline: 2.0535x; 1.1496x over previous
//
#include <hip/hip_runtime.h>

#define N_NODES 100000
#define N_EDGES 3200000
#define D 64
#define G_GRAPHS 64
#define L_LAYERS 5
#define BN_EPS 1e-5f
#define RPW 8
#define NBUCK 196     // dst>>9 buckets (512 nodes each; 196*512 >= 100000)
#define BSHIFT 9
#define BMASK 511
#define NPB 512       // partition blocks
#define EPB 6250      // edges per partition block (512*6250 = E)
#define TOTC (NBUCK * NPB)   // 100352 flattened (bucket, block) counts
#define SCAN_CH 392   // 256 blocks x 392 >= TOTC

typedef __fp16 h2 __attribute__((ext_vector_type(2)));
union h2u { unsigned u; h2 h; };

__device__ __forceinline__ unsigned pkf16(float a, float b) {
    h2u x; x.h = __builtin_amdgcn_cvt_pkrtz(a, b); return x.u;
}
__device__ __forceinline__ float dot2(unsigned a, unsigned b, float c) {
    h2u x, y; x.u = a; y.u = b;
    return __builtin_amdgcn_fdot2(x.h, y.h, c, false);
}

__device__ __forceinline__ unsigned short f2bf(float f) {  // RNE f32->bf16
    unsigned int u = __float_as_uint(f);
    u += 0x7FFFu + ((u >> 16) & 1u);
    return (unsigned short)(u >> 16);
}
__device__ __forceinline__ float bf2f(unsigned short v) {
    return __uint_as_float((unsigned int)v << 16);
}

// async global->LDS, 16B per lane; LDS dest is wave-uniform base + lane*16
__device__ __forceinline__ void gload_lds16(const void* g, void* l) {
    __builtin_amdgcn_global_load_lds(
        (const __attribute__((address_space(1))) unsigned int*)g,
        (__attribute__((address_space(3))) unsigned int*)l, 16, 0, 0);
}

__device__ __forceinline__ unsigned quant15(float a) {
    float q = fminf(fmaxf((a + 8.0f) * 2048.0f, 0.0f), 32767.0f);
    return (unsigned)__float2int_rn(q);
}

// ---------------- x -> bf16 -------------------------------------------------
__global__ __launch_bounds__(256) void xcvt_kernel(const float* __restrict__ x,
                                                   ushort* __restrict__ xbf) {
    const float4* x4 = (const float4*)x;
    ushort4* o4 = (ushort4*)xbf;
    const int total = N_NODES * D / 4;
    for (int i = blockIdx.x * blockDim.x + threadIdx.x; i < total;
         i += gridDim.x * blockDim.x) {
        float4 v = x4[i];
        ushort4 o;
        o.x = f2bf(v.x); o.y = f2bf(v.y); o.z = f2bf(v.z); o.w = f2bf(v.w);
        o4[i] = o;
    }
}

// ---------------- pass A: per-block bucket histogram -------------------------
__global__ __launch_bounds__(256) void hist512_kernel(const int* __restrict__ ei,
                                                      int* __restrict__ gcount) {
    __shared__ int cnt[NBUCK];
    const int tid = threadIdx.x, b = blockIdx.x;
    if (tid < NBUCK) cnt[tid] = 0;
    __syncthreads();
    const int ebase = b * EPB, eend = ebase + EPB;
    for (int r = 0; r < 25; ++r) {
        int e = ebase + r * 256 + tid;
        if (e < eend) atomicAdd(&cnt[ei[N_EDGES + e] >> BSHIFT], 1);
    }
    __syncthreads();
    if (tid < NBUCK) gcount[tid * NPB + b] = cnt[tid];   // bucket-major
}

// ---------------- pass B: parallel exclusive scan of 196*512 counts ----------
__global__ __launch_bounds__(256) void scan_partial(const int* __restrict__ gcount,
                                                    int* __restrict__ bsum) {
    __shared__ int sc[256];
    int b = blockIdx.x, t = threadIdx.x;
    int s = b * SCAN_CH, e = min(s + SCAN_CH, TOTC);
    int sum = 0;
    for (int idx = s + t; idx < e; idx += 256) sum += gcount[idx];
    sc[t] = sum;
    __syncthreads();
    for (int o = 128; o; o >>= 1) {
        if (t < o) sc[t] += sc[t + o];
        __syncthreads();
    }
    if (!t) bsum[b] = sc[0];
}

__global__ __launch_bounds__(256) void scan_base(const int* __restrict__ bsum,
                                                 int* __restrict__ bbase,
                                                 int* __restrict__ bucketbase) {
    __shared__ int sc[256];
    int t = threadIdx.x;
    int v = bsum[t];
    sc[t] = v;
    __syncthreads();
    for (int o = 1; o < 256; o <<= 1) {
        int x = (t >= o) ? sc[t - o] : 0;
        __syncthreads();
        sc[t] += x;
        __syncthreads();
    }
    bbase[t] = sc[t] - v;
    if (t == 0) bucketbase[NBUCK] = N_EDGES;
}

__global__ __launch_bounds__(256) void scan_apply(const int* __restrict__ gcount,
                                                  const int* __restrict__ bbase,
                                                  int* __restrict__ ofs,
                                                  int* __restrict__ bucketbase) {
    __shared__ int sc[256];
    int b = blockIdx.x, t = threadIdx.x;
    int s = b * SCAN_CH, e = min(s + SCAN_CH, TOTC);
    int base = bbase[b];
    for (int t0 = s; t0 < e; t0 += 256) {
        int idx = t0 + t;
        int v = (idx < e) ? gcount[idx] : 0;
        sc[t] = v;
        __syncthreads();
        for (int o = 1; o < 256; o <<= 1) {
            int x = (t >= o) ? sc[t - o] : 0;
            __syncthreads();
            sc[t] += x;
            __syncthreads();
        }
        if (idx < e) {
            int ex = base + sc[t] - v;
            ofs[idx] = ex;
            if ((idx & (NPB - 1)) == 0) bucketbase[idx / NPB] = ex;
        }
        base += sc[255];
        __syncthreads();
    }
}

// ---------------- pass C: ordered partition write (stream-contiguous) --------
// entry: x = src, y = (dst & 511) | (attr15 << 9)
__global__ __launch_bounds__(256) void part_kernel(const int* __restrict__ ei,
                                                   const float* __restrict__ ea,
                                                   const int* __restrict__ ofs,
                                                   uint2* __restrict__ inter) {
    __shared__ int cur[NBUCK];
    const int tid = threadIdx.x, b = blockIdx.x;
    if (tid < NBUCK) cur[tid] = ofs[tid * NPB + b];
    __syncthreads();
    const int ebase = b * EPB, eend = ebase + EPB;
    for (int r = 0; r < 25; ++r) {
        int e = ebase + r * 256 + tid;
        if (e < eend) {
            int s = ei[e];
            int d = ei[N_EDGES + e];
            float a = ea[e];
            int k = d >> BSHIFT;
            int p = atomicAdd(&cur[k], 1);
            uint2 v;
            v.x = (unsigned)s;
            v.y = (unsigned)(d & BMASK) | (quant15(a) << BSHIFT);
            inter[p] = v;
        }
    }
}

// ---------------- pass D: per-bucket exact sort (196 blocks, L2-local) -------
__global__ __launch_bounds__(256) void bucket_kernel(const uint2* __restrict__ inter,
                                                     const int* __restrict__ bucketbase,
                                                     unsigned* __restrict__ perm,
                                                     int* __restrict__ row_ptr) {
    __shared__ int hist[512];
    __shared__ int part[256];
    const int b = blockIdx.x, t = threadIdx.x;
    const int beg = bucketbase[b], end = bucketbase[b + 1];
    const int cnt = end - beg;
    const uint2* reg = inter + beg;
    const int n0 = b << BSHIFT;
    const int nn = min(512, N_NODES - n0);
    hist[t] = 0; hist[t + 256] = 0;
    __syncthreads();
    for (int i = t; i < cnt; i += 256)
        atomicAdd(&hist[reg[i].y & BMASK], 1);
    __syncthreads();
    int h0 = hist[2 * t], h1 = hist[2 * t + 1];
    int s = h0 + h1;
    part[t] = s;
    __syncthreads();
    for (int o = 1; o < 256; o <<= 1) {
        int v = (t >= o) ? part[t - o] : 0;
        __syncthreads();
        part[t] += v;
        __syncthreads();
    }
    int ex = beg + part[t] - s;
    if (2 * t < nn)     row_ptr[n0 + 2 * t] = ex;
    if (2 * t + 1 < nn) row_ptr[n0 + 2 * t + 1] = ex + h0;
    hist[2 * t] = ex;
    hist[2 * t + 1] = ex + h0;
    __syncthreads();
    for (int i = t; i < cnt; i += 256) {
        uint2 v = reg[i];
        int p = atomicAdd(&hist[v.y & BMASK], 1);
        perm[p] = (v.x << 15) | (v.y >> BSHIFT);
    }
    if (b == NBUCK - 1 && t == 0) row_ptr[N_NODES] = N_EDGES;
}

// ---------------- fused GINE layer (R13, unchanged) --------------------------
__global__ __launch_bounds__(256, 4) void layer_kernel(
    const ushort* __restrict__ hbf,      // [N][D] bf16
    const int* __restrict__ row_ptr,
    const unsigned* __restrict__ perm,
    const float* __restrict__ eps, int layer,
    const float* __restrict__ edgeW, const float* __restrict__ edgeB,
    const float* __restrict__ W1, const float* __restrict__ b1,
    const float* __restrict__ bng, const float* __restrict__ bnb,
    const float* __restrict__ W2, const float* __restrict__ b2,
    const int* __restrict__ batch,
    ushort* __restrict__ hout,           // [N][D] bf16
    float* __restrict__ pooled /* [G][D] this layer */) {
    __shared__ unsigned Wp1[32 * 64];                   // 8 KB f16x2 pairs
    __shared__ __align__(16) ushort stage[4][3][1024];  // 24 KB: 3-slot ring/wave
    __shared__ __align__(16) unsigned pbuf[4][512];     // 8 KB: perm segment/wave

    const float inv_std = rsqrtf(1.0f + BN_EPS);
    const int tid = threadIdx.x;
    for (int idx = tid; idx < 32 * 64; idx += 256) {
        int kp = idx >> 6, c = idx & 63;
        float s = bng[c] * inv_std;
        Wp1[idx] = pkf16(W1[(2 * kp) * 64 + c] * s, W1[(2 * kp + 1) * 64 + c] * s);
    }
    __syncthreads();

    const int lane = tid & 63;
    const int q = lane & 15;
    const int grp = lane >> 4;
    const int wid = tid >> 6;
    const int wv = blockIdx.x * 4 + wid;
    const int r0 = wv * RPW;          // N = 12500*8 exactly
    if (r0 >= N_NODES) return;

    // W2 fragments in registers: 8 x uint4 (f16x2 packed)
    uint4 w2r[8];
    #pragma unroll
    for (int kk2 = 0; kk2 < 8; ++kk2) {
        int kp = (grp << 3) + kk2;
        float4 ra = *(const float4*)&W2[(2 * kp) * 64 + (q << 2)];
        float4 rb = *(const float4*)&W2[(2 * kp + 1) * 64 + (q << 2)];
        w2r[kk2] = make_uint4(pkf16(ra.x, rb.x), pkf16(ra.y, rb.y),
                              pkf16(ra.z, rb.z), pkf16(ra.w, rb.w));
    }

    int rpv = 0;
    if (lane < 9) rpv = row_ptr[r0 + lane];
    int cval = __shfl(rpv, lane + 1) - rpv;    // degree, valid lane<8
    int bval = 0;
    if (lane < RPW) bval = batch[r0 + lane];
    const int segbase = __shfl(rpv, 0);
    const int seglen  = __shfl(rpv, 8) - segbase;

    const float ev = 1.0f + eps[layer];
    const float QDEC = 4.8828125e-4f;  // 1/2048
    float w4[4], b4[4], blv1[4], blv2[4];
    {
        float4 t = ((const float4*)edgeW)[q];
        w4[0] = t.x; w4[1] = t.y; w4[2] = t.z; w4[3] = t.w;
        float4 u = ((const float4*)edgeB)[q];
        b4[0] = u.x; b4[1] = u.y; b4[2] = u.z; b4[3] = u.w;
        float4 g = ((const float4*)bng)[q];
        float4 v = ((const float4*)b1)[q];
        float4 bb = ((const float4*)bnb)[q];
        blv1[0] = fmaf(v.x, g.x * inv_std, bb.x);
        blv1[1] = fmaf(v.y, g.y * inv_std, bb.y);
        blv1[2] = fmaf(v.z, g.z * inv_std, bb.z);
        blv1[3] = fmaf(v.w, g.w * inv_std, bb.w);
        float4 w = ((const float4*)b2)[q];
        blv2[0] = w.x; blv2[1] = w.y; blv2[2] = w.z; blv2[3] = w.w;
    }
    const ushort4* h4 = (const ushort4*)hbf;
    ushort4* o4 = (ushort4*)hout;

    // ---- pooling ----
    int cur_g = -1;
    float rm[4] = {0.f, 0.f, 0.f, 0.f};
    auto flush_pool = [&]() {
        if (cur_g >= 0 && grp == 0) {
            unsigned* p = (unsigned*)&pooled[cur_g * D + 4 * q];
            atomicMax(p + 0, __float_as_uint(rm[0]));
            atomicMax(p + 1, __float_as_uint(rm[1]));
            atomicMax(p + 2, __float_as_uint(rm[2]));
            atomicMax(p + 3, __float_as_uint(rm[3]));
        }
    };
    auto pool = [&](int bg, const float* y) {
        if (bg != cur_g) {
            flush_pool();
            cur_g = bg;
            rm[0] = y[0]; rm[1] = y[1]; rm[2] = y[2]; rm[3] = y[3];
        } else {
            rm[0] = fmaxf(rm[0], y[0]); rm[1] = fmaxf(rm[1], y[1]);
            rm[2] = fmaxf(rm[2], y[2]); rm[3] = fmaxf(rm[3], y[3]);
        }
    };

    // ---- shared row finalizer (pairs rows; GEMM1 LDS, GEMM2 regs) ----
    bool havePend = false;
    int aiPend = 0;
    unsigned zpP0 = 0, zpP1 = 0;
    auto finrow = [&](int ai, unsigned zc0, unsigned zc1) {
        if (!havePend) { zpP0 = zc0; zpP1 = zc1; aiPend = ai; havePend = true; return; }
        havePend = false;
        float pA[4] = {0,0,0,0}, pB[4] = {0,0,0,0};
        #pragma unroll
        for (int kk2 = 0; kk2 < 8; ++kk2) {
            int kp = (grp << 3) + kk2;
            int srcl = (grp << 2) + (kk2 >> 1);
            unsigned zA = __shfl((kk2 & 1) ? zpP1 : zpP0, srcl);
            unsigned zB = __shfl((kk2 & 1) ? zc1 : zc0, srcl);
            uint4 wq = *(const uint4*)&Wp1[(kp << 6) + (q << 2)];
            pA[0] = dot2(zA, wq.x, pA[0]); pA[1] = dot2(zA, wq.y, pA[1]);
            pA[2] = dot2(zA, wq.z, pA[2]); pA[3] = dot2(zA, wq.w, pA[3]);
            pB[0] = dot2(zB, wq.x, pB[0]); pB[1] = dot2(zB, wq.y, pB[1]);
            pB[2] = dot2(zB, wq.z, pB[2]); pB[3] = dot2(zB, wq.w, pB[3]);
        }
        float y1A[4], y1B[4];
        #pragma unroll
        for (int c = 0; c < 4; ++c) {
            float sA = pA[c];
            sA += __shfl_xor(sA, 16); sA += __shfl_xor(sA, 32);
            y1A[c] = fmaxf(sA + blv1[c], 0.f);
            float sB = pB[c];
            sB += __shfl_xor(sB, 16); sB += __shfl_xor(sB, 32);
            y1B[c] = fmaxf(sB + blv1[c], 0.f);
        }
        unsigned yA0 = pkf16(y1A[0], y1A[1]), yA1 = pkf16(y1A[2], y1A[3]);
        unsigned yB0 = pkf16(y1B[0], y1B[1]), yB1 = pkf16(y1B[2], y1B[3]);
        float qA[4] = {0,0,0,0}, qB[4] = {0,0,0,0};
        #pragma unroll
        for (int kk2 = 0; kk2 < 8; ++kk2) {
            int srcl = (grp << 2) + (kk2 >> 1);
            unsigned zA = __shfl((kk2 & 1) ? yA1 : yA0, srcl);
            unsigned zB = __shfl((kk2 & 1) ? yB1 : yB0, srcl);
            uint4 wq = w2r[kk2];
            qA[0] = dot2(zA, wq.x, qA[0]); qA[1] = dot2(zA, wq.y, qA[1]);
            qA[2] = dot2(zA, wq.z, qA[2]); qA[3] = dot2(zA, wq.w, qA[3]);
            qB[0] = dot2(zB, wq.x, qB[0]); qB[1] = dot2(zB, wq.y, qB[1]);
            qB[2] = dot2(zB, wq.z, qB[2]); qB[3] = dot2(zB, wq.w, qB[3]);
        }
        float y2A[4], y2B[4];
        #pragma unroll
        for (int c = 0; c < 4; ++c) {
            float sA = qA[c];
            sA += __shfl_xor(sA, 16); sA += __shfl_xor(sA, 32);
            y2A[c] = fmaxf(sA + blv2[c], 0.f);
            float sB = qB[c];
            sB += __shfl_xor(sB, 16); sB += __shfl_xor(sB, 32);
            y2B[c] = fmaxf(sB + blv2[c], 0.f);
        }
        if (grp == 0) {
            ushort4 o;
            o.x = f2bf(y2A[0]); o.y = f2bf(y2A[1]);
            o.z = f2bf(y2A[2]); o.w = f2bf(y2A[3]);
            o4[(size_t)(r0 + aiPend) * 16 + q] = o;
            ushort4 o2;
            o2.x = f2bf(y2B[0]); o2.y = f2bf(y2B[1]);
            o2.z = f2bf(y2B[2]); o2.w = f2bf(y2B[3]);
            o4[(size_t)(r0 + ai) * 16 + q] = o2;
        }
        pool(__shfl(bval, aiPend), y2A);
        pool(__shfl(bval, ai), y2B);
    };

    if (seglen <= 512) {
        // ---- fast path: perm segment in LDS, depth-2 async gather ----
        if (seglen > 0) {
            gload_lds16(perm + segbase + lane * 4, &pbuf[wid][0]);
            if (seglen > 256)
                gload_lds16(perm + segbase + 256 + lane * 4, &pbuf[wid][256]);
        }
        asm volatile("s_waitcnt vmcnt(0)" ::: "memory");  // pbuf ready

        auto nchunks = [&](int i) { return (__shfl(cval, i) + 15) >> 4; };
        int nTot = 0;
        #pragma unroll
        for (int i = 0; i < RPW; ++i) nTot += nchunks(i);

        int i_iss = 0, c_iss = 0;
        while (i_iss < RPW && nchunks(i_iss) == 0) ++i_iss;
        auto issue1 = [&](int slot) {
            int rb = __shfl(rpv, i_iss) - segbase;
            int so = rb + (c_iss << 4);
            ushort* sb = &stage[wid][slot][0];
            int eloc = lane >> 3, sub = lane & 7;
            #pragma unroll
            for (int j = 0; j < 2; ++j) {
                int idx = min(so + (j << 3) + eloc, 511);
                unsigned pe = pbuf[wid][idx];
                gload_lds16(hbf + (size_t)(pe >> 15) * D + sub * 8, sb + j * 512);
            }
            ++c_iss;
            while (i_iss < RPW) {
                if (c_iss < nchunks(i_iss)) break;
                ++i_iss; c_iss = 0;
            }
        };
        auto accumulate = [&](const ushort* sb, int rb, int ebase, int cr, float* agg) {
            #pragma unroll
            for (int k = 0; k < 4; ++k) {
                int eidx = (k << 2) | grp;
                int idx = min(rb + ebase + eidx, 511);
                unsigned pe = pbuf[wid][idx];
                float m = (ebase + eidx < cr) ? 1.0f : 0.0f;
                float a = fmaf((float)(pe & 0x7FFFu), QDEC, -8.0f);
                ushort4 hv = *(const ushort4*)(sb + (eidx << 6) + (q << 2));
                agg[0] = fmaf(m, fmaxf(fmaf(a, w4[0], b4[0]) + bf2f(hv.x), 0.f), agg[0]);
                agg[1] = fmaf(m, fmaxf(fmaf(a, w4[1], b4[1]) + bf2f(hv.y), 0.f), agg[1]);
                agg[2] = fmaf(m, fmaxf(fmaf(a, w4[2], b4[2]) + bf2f(hv.z), 0.f), agg[2]);
                agg[3] = fmaf(m, fmaxf(fmaf(a, w4[3], b4[3]) + bf2f(hv.w), 0.f), agg[3]);
            }
        };

        int nIss = 0, sIss = 0, nCon = 0, sCon = 0;
        if (nIss < nTot) { issue1(sIss); sIss = 1; ++nIss; }
        if (nIss < nTot) { issue1(sIss); sIss = 2; ++nIss; }

        for (int ai = 0; ai < RPW; ++ai) {
            int cr = __shfl(cval, ai);
            int nch = (cr + 15) >> 4;
            int rb = __shfl(rpv, ai) - segbase;
            ushort4 hs4 = h4[(size_t)(r0 + ai) * 16 + q];   // self row
            float agg[4] = {0.f, 0.f, 0.f, 0.f};
            for (int ac = 0; ac < nch; ++ac) {
                if (nIss < nTot) {
                    issue1(sIss);
                    sIss = (sIss == 2) ? 0 : sIss + 1;
                    ++nIss;
                    asm volatile("s_waitcnt vmcnt(4)" ::: "memory");
                } else if (nIss - nCon == 2) {
                    asm volatile("s_waitcnt vmcnt(2)" ::: "memory");
                } else {
                    asm volatile("s_waitcnt vmcnt(0)" ::: "memory");
                }
                accumulate(&stage[wid][sCon][0], rb, ac << 4, cr, agg);
                sCon = (sCon == 2) ? 0 : sCon + 1;
                ++nCon;
            }
            #pragma unroll
            for (int c = 0; c < 4; ++c) {
                agg[c] += __shfl_xor(agg[c], 16);
                agg[c] += __shfl_xor(agg[c], 32);
            }
            float z0 = fmaf(ev, bf2f(hs4.x), agg[0]);
            float z1 = fmaf(ev, bf2f(hs4.y), agg[1]);
            float z2 = fmaf(ev, bf2f(hs4.z), agg[2]);
            float z3 = fmaf(ev, bf2f(hs4.w), agg[3]);
            finrow(ai, pkf16(z0, z1), pkf16(z2, z3));
        }
    } else {
        // ---- rare fallback: serial direct gather (no staging) ----
        for (int ai = 0; ai < RPW; ++ai) {
            int cr = __shfl(cval, ai);
            int rbg = __shfl(rpv, ai);
            ushort4 hs4 = h4[(size_t)(r0 + ai) * 16 + q];
            float agg[4] = {0.f, 0.f, 0.f, 0.f};
            for (int k = grp; k < cr; k += 4) {
                unsigned pe = perm[rbg + k];
                float a = fmaf((float)(pe & 0x7FFFu), QDEC, -8.0f);
                ushort4 hv = h4[(size_t)(pe >> 15) * 16 + q];
                agg[0] += fmaxf(fmaf(a, w4[0], b4[0]) + bf2f(hv.x), 0.f);
                agg[1] += fmaxf(fmaf(a, w4[1], b4[1]) + bf2f(hv.y), 0.f);
                agg[2] += fmaxf(fmaf(a, w4[2], b4[2]) + bf2f(hv.z), 0.f);
                agg[3] += fmaxf(fmaf(a, w4[3], b4[3]) + bf2f(hv.w), 0.f);
            }
            #pragma unroll
            for (int c = 0; c < 4; ++c) {
                agg[c] += __shfl_xor(agg[c], 16);
                agg[c] += __shfl_xor(agg[c], 32);
            }
            float z0 = fmaf(ev, bf2f(hs4.x), agg[0]);
            float z1 = fmaf(ev, bf2f(hs4.y), agg[1]);
            float z2 = fmaf(ev, bf2f(hs4.z), agg[2]);
            float z3 = fmaf(ev, bf2f(hs4.w), agg[3]);
            finrow(ai, pkf16(z0, z1), pkf16(z2, z3));
        }
    }
    flush_pool();
}

// ---------------- MLP head ---------------------------------------------------
__global__ __launch_bounds__(256) void mlp_kernel(
    const float* __restrict__ pooled,  // [5][G][D]
    const float* __restrict__ l1W, const float* __restrict__ l1b,
    const float* __restrict__ l2W, const float* __restrict__ l2b,
    float* __restrict__ out) {
    __shared__ float gl[5 * D];
    __shared__ float tl[4 * D];
    int gid = blockIdx.x;
    int tid = threadIdx.x;
    for (int idx = tid; idx < 5 * D; idx += 256) {
        int k = idx >> 6;
        int d = idx & 63;
        gl[idx] = pooled[k * (G_GRAPHS * D) + gid * D + d];
    }
    __syncthreads();
    {
        float acc = l1b[tid];
        for (int m = 0; m < 5 * D; ++m)
            acc = fmaf(gl[m], l1W[m * 256 + tid], acc);
        tl[tid] = fmaxf(acc, 0.0f);
    }
    __syncthreads();
    if (tid < 5) {
        float acc = l2b[tid];
        for (int m = 0; m < 4 * D; ++m)
            acc = fmaf(tl[m], l2W[m * 5 + tid], acc);
        out[gid * 5 + tid] = acc;
    }
}

extern "C" void kernel_launch(void* const* d_in, const int* in_sizes, int n_in,
                              void* d_out, int out_size, void* d_ws, size_t ws_size,
                              hipStream_t stream) {
    const float* x     = (const float*)d_in[0];
    const int*   ei    = (const int*)d_in[1];
    const float* ea    = (const float*)d_in[2];
    const int*   batch = (const int*)d_in[3];
    const float* eps   = (const float*)d_in[4];
    const float* edgeW = (const float*)d_in[5];
    const float* edgeB = (const float*)d_in[6];
    const float* W1    = (const float*)d_in[7];
    const float* b1    = (const float*)d_in[8];
    const float* bng   = (const float*)d_in[9];
    const float* bnb   = (const float*)d_in[10];
    const float* W2    = (const float*)d_in[11];
    const float* b2    = (const float*)d_in[12];
    const float* l1W   = (const float*)d_in[13];
    const float* l1b   = (const float*)d_in[14];
    const float* l2W   = (const float*)d_in[15];
    const float* l2b   = (const float*)d_in[16];
    float* out = (float*)d_out;

    char* ws = (char*)d_ws;
    size_t nbf = (size_t)N_NODES * D * sizeof(ushort);  // 12.8 MB
    size_t off = 0;
    ushort* hbfA  = (ushort*)(ws + off); off += nbf;
    ushort* hbfB  = (ushort*)(ws + off); off += nbf;
    float* pooled = (float*)(ws + off);  off += (size_t)L_LAYERS * G_GRAPHS * D * sizeof(float);
    off = (off + 15) & ~(size_t)15;
    unsigned* perm = (unsigned*)(ws + off); off += (size_t)N_EDGES * sizeof(unsigned); // 12.8 MB
    int* row_ptr  = (int*)(ws + off);    off += (size_t)(N_NODES + 1) * sizeof(int);
    int* gcount   = (int*)(ws + off);    off += (size_t)TOTC * sizeof(int);   // 401 KB
    int* ofs      = (int*)(ws + off);    off += (size_t)TOTC * sizeof(int);   // 401 KB
    int* bucketbase = (int*)(ws + off);  off += (NBUCK + 4) * sizeof(int);
    int* bsum     = (int*)(ws + off);    off += 256 * sizeof(int);
    int* bbase    = (int*)(ws + off);    off += 256 * sizeof(int);
    off = (off + 15) & ~(size_t)15;
    uint2* inter  = (uint2*)(ws + off);  off += (size_t)N_EDGES * sizeof(uint2);  // 25.6 MB

    hipMemsetAsync(pooled, 0, (size_t)L_LAYERS * G_GRAPHS * D * sizeof(float), stream);

    xcvt_kernel<<<1024, 256, 0, stream>>>(x, hbfA);
    hist512_kernel<<<NPB, 256, 0, stream>>>(ei, gcount);
    scan_partial<<<256, 256, 0, stream>>>(gcount, bsum);
    scan_base<<<1, 256, 0, stream>>>(bsum, bbase, bucketbase);
    scan_apply<<<256, 256, 0, stream>>>(gcount, bbase, ofs, bucketbase);
    part_kernel<<<NPB, 256, 0, stream>>>(ei, ea, ofs, inter);
    bucket_kernel<<<NBUCK, 256, 0, stream>>>(inter, bucketbase, perm, row_ptr);

    const int waves  = (N_NODES + RPW - 1) / RPW;   // 12500
    const int blocks = (waves + 3) / 4;             // 3125

    const ushort* hcur = hbfA;
    for (int i = 0; i < L_LAYERS; ++i) {
        ushort* hnext = (i & 1) ? hbfA : hbfB;
        layer_kernel<<<blocks, 256, 0, stream>>>(
            hcur, row_ptr, perm, eps, i,
            edgeW + i * D, edgeB + i * D,
            W1 + i * D * D, b1 + i * D,
            bng + i * D, bnb + i * D,
            W2 + i * D * D, b2 + i * D,
            batch, hnext, pooled + i * G_GRAPHS * D);
        hcur = hnext;
    }
    mlp_kernel<<<G_GRAPHS, 256, 0, stream>>>(pooled, l1W, l1b, l2W, l2b, out);
}

// Round 15
// 747.021 us; speedup vs baseline: 2.6322x; 1.2818x over previous
//
#include <hip/hip_runtime.h>

#define N_NODES 100000
#define N_EDGES 3200000
#define D 64
#define G_GRAPHS 64
#define L_LAYERS 5
#define BN_EPS 1e-5f
#define RPW 8
#define NBUCK 196     // dst>>9 buckets (512 nodes each; 196*512 >= 100000)
#define BSHIFT 9
#define BMASK 511
#define NPB 512       // partition blocks
#define EPB 6250      // edges per partition block (512*6250 = E)
#define TOTC (NBUCK * NPB)   // 100352 flattened (bucket, block) counts
#define SCAN_CH 392   // 256 blocks x 392 >= TOTC

typedef __fp16 h2 __attribute__((ext_vector_type(2)));
union h2u { unsigned u; h2 h; };
typedef short v8s __attribute__((ext_vector_type(8)));   // 8 bf16 (MFMA A/B frag)
typedef float v4f __attribute__((ext_vector_type(4)));   // MFMA C/D frag

__device__ __forceinline__ unsigned pkf16(float a, float b) {
    h2u x; x.h = __builtin_amdgcn_cvt_pkrtz(a, b); return x.u;
}

__device__ __forceinline__ unsigned short f2bf(float f) {  // RNE f32->bf16
    unsigned int u = __float_as_uint(f);
    u += 0x7FFFu + ((u >> 16) & 1u);
    return (unsigned short)(u >> 16);
}
__device__ __forceinline__ float bf2f(unsigned short v) {
    return __uint_as_float((unsigned int)v << 16);
}

// async global->LDS, 16B per lane; LDS dest is wave-uniform base + lane*16
__device__ __forceinline__ void gload_lds16(const void* g, void* l) {
    __builtin_amdgcn_global_load_lds(
        (const __attribute__((address_space(1))) unsigned int*)g,
        (__attribute__((address_space(3))) unsigned int*)l, 16, 0, 0);
}

__device__ __forceinline__ unsigned quant15(float a) {
    float q = fminf(fmaxf((a + 8.0f) * 2048.0f, 0.0f), 32767.0f);
    return (unsigned)__float2int_rn(q);
}

// ---------------- x -> bf16 -------------------------------------------------
__global__ __launch_bounds__(256) void xcvt_kernel(const float* __restrict__ x,
                                                   ushort* __restrict__ xbf) {
    const float4* x4 = (const float4*)x;
    ushort4* o4 = (ushort4*)xbf;
    const int total = N_NODES * D / 4;
    for (int i = blockIdx.x * blockDim.x + threadIdx.x; i < total;
         i += gridDim.x * blockDim.x) {
        float4 v = x4[i];
        ushort4 o;
        o.x = f2bf(v.x); o.y = f2bf(v.y); o.z = f2bf(v.z); o.w = f2bf(v.w);
        o4[i] = o;
    }
}

// ---------------- pass A: per-block bucket histogram -------------------------
__global__ __launch_bounds__(256) void hist512_kernel(const int* __restrict__ ei,
                                                      int* __restrict__ gcount) {
    __shared__ int cnt[NBUCK];
    const int tid = threadIdx.x, b = blockIdx.x;
    if (tid < NBUCK) cnt[tid] = 0;
    __syncthreads();
    const int ebase = b * EPB, eend = ebase + EPB;
    for (int r = 0; r < 25; ++r) {
        int e = ebase + r * 256 + tid;
        if (e < eend) atomicAdd(&cnt[ei[N_EDGES + e] >> BSHIFT], 1);
    }
    __syncthreads();
    if (tid < NBUCK) gcount[tid * NPB + b] = cnt[tid];   // bucket-major
}

// ---------------- pass B: parallel exclusive scan of 196*512 counts ----------
__global__ __launch_bounds__(256) void scan_partial(const int* __restrict__ gcount,
                                                    int* __restrict__ bsum) {
    __shared__ int sc[256];
    int b = blockIdx.x, t = threadIdx.x;
    int s = b * SCAN_CH, e = min(s + SCAN_CH, TOTC);
    int sum = 0;
    for (int idx = s + t; idx < e; idx += 256) sum += gcount[idx];
    sc[t] = sum;
    __syncthreads();
    for (int o = 128; o; o >>= 1) {
        if (t < o) sc[t] += sc[t + o];
        __syncthreads();
    }
    if (!t) bsum[b] = sc[0];
}

__global__ __launch_bounds__(256) void scan_base(const int* __restrict__ bsum,
                                                 int* __restrict__ bbase,
                                                 int* __restrict__ bucketbase) {
    __shared__ int sc[256];
    int t = threadIdx.x;
    int v = bsum[t];
    sc[t] = v;
    __syncthreads();
    for (int o = 1; o < 256; o <<= 1) {
        int x = (t >= o) ? sc[t - o] : 0;
        __syncthreads();
        sc[t] += x;
        __syncthreads();
    }
    bbase[t] = sc[t] - v;
    if (t == 0) bucketbase[NBUCK] = N_EDGES;
}

__global__ __launch_bounds__(256) void scan_apply(const int* __restrict__ gcount,
                                                  const int* __restrict__ bbase,
                                                  int* __restrict__ ofs,
                                                  int* __restrict__ bucketbase) {
    __shared__ int sc[256];
    int b = blockIdx.x, t = threadIdx.x;
    int s = b * SCAN_CH, e = min(s + SCAN_CH, TOTC);
    int base = bbase[b];
    for (int t0 = s; t0 < e; t0 += 256) {
        int idx = t0 + t;
        int v = (idx < e) ? gcount[idx] : 0;
        sc[t] = v;
        __syncthreads();
        for (int o = 1; o < 256; o <<= 1) {
            int x = (t >= o) ? sc[t - o] : 0;
            __syncthreads();
            sc[t] += x;
            __syncthreads();
        }
        if (idx < e) {
            int ex = base + sc[t] - v;
            ofs[idx] = ex;
            if ((idx & (NPB - 1)) == 0) bucketbase[idx / NPB] = ex;
        }
        base += sc[255];
        __syncthreads();
    }
}

// ---------------- pass C: ordered partition write (stream-contiguous) --------
// entry: x = src, y = (dst & 511) | (attr15 << 9)
__global__ __launch_bounds__(256) void part_kernel(const int* __restrict__ ei,
                                                   const float* __restrict__ ea,
                                                   const int* __restrict__ ofs,
                                                   uint2* __restrict__ inter) {
    __shared__ int cur[NBUCK];
    const int tid = threadIdx.x, b = blockIdx.x;
    if (tid < NBUCK) cur[tid] = ofs[tid * NPB + b];
    __syncthreads();
    const int ebase = b * EPB, eend = ebase + EPB;
    for (int r = 0; r < 25; ++r) {
        int e = ebase + r * 256 + tid;
        if (e < eend) {
            int s = ei[e];
            int d = ei[N_EDGES + e];
            float a = ea[e];
            int k = d >> BSHIFT;
            int p = atomicAdd(&cur[k], 1);
            uint2 v;
            v.x = (unsigned)s;
            v.y = (unsigned)(d & BMASK) | (quant15(a) << BSHIFT);
            inter[p] = v;
        }
    }
}

// ---------------- pass D: per-bucket exact sort (196 blocks, L2-local) -------
__global__ __launch_bounds__(256) void bucket_kernel(const uint2* __restrict__ inter,
                                                     const int* __restrict__ bucketbase,
                                                     unsigned* __restrict__ perm,
                                                     int* __restrict__ row_ptr) {
    __shared__ int hist[512];
    __shared__ int part[256];
    const int b = blockIdx.x, t = threadIdx.x;
    const int beg = bucketbase[b], end = bucketbase[b + 1];
    const int cnt = end - beg;
    const uint2* reg = inter + beg;
    const int n0 = b << BSHIFT;
    const int nn = min(512, N_NODES - n0);
    hist[t] = 0; hist[t + 256] = 0;
    __syncthreads();
    for (int i = t; i < cnt; i += 256)
        atomicAdd(&hist[reg[i].y & BMASK], 1);
    __syncthreads();
    int h0 = hist[2 * t], h1 = hist[2 * t + 1];
    int s = h0 + h1;
    part[t] = s;
    __syncthreads();
    for (int o = 1; o < 256; o <<= 1) {
        int v = (t >= o) ? part[t - o] : 0;
        __syncthreads();
        part[t] += v;
        __syncthreads();
    }
    int ex = beg + part[t] - s;
    if (2 * t < nn)     row_ptr[n0 + 2 * t] = ex;
    if (2 * t + 1 < nn) row_ptr[n0 + 2 * t + 1] = ex + h0;
    hist[2 * t] = ex;
    hist[2 * t + 1] = ex + h0;
    __syncthreads();
    for (int i = t; i < cnt; i += 256) {
        uint2 v = reg[i];
        int p = atomicAdd(&hist[v.y & BMASK], 1);
        perm[p] = (v.x << 15) | (v.y >> BSHIFT);
    }
    if (b == NBUCK - 1 && t == 0) row_ptr[N_NODES] = N_EDGES;
}

// ---------------- fused GINE layer (R14 gather + MFMA GEMM phase) ------------
// Gather unchanged: pbuf perm segment, 3-slot stage ring, depth-2 vmcnt(4/2/0).
// z rows -> swizzled zbuf (bf16); then per-wave MFMA: Y1=relu(bn(Z@W1)),
// H=relu(Y1@W2) via 16x mfma_f32_16x16x32_bf16 (B-frags prebuilt in LDS).
__global__ __launch_bounds__(256, 3) void layer_kernel(
    const ushort* __restrict__ hbf,      // [N][D] bf16
    const int* __restrict__ row_ptr,
    const unsigned* __restrict__ perm,
    const float* __restrict__ eps, int layer,
    const float* __restrict__ edgeW, const float* __restrict__ edgeB,
    const float* __restrict__ W1, const float* __restrict__ b1,
    const float* __restrict__ bng, const float* __restrict__ bnb,
    const float* __restrict__ W2, const float* __restrict__ b2,
    const int* __restrict__ batch,
    ushort* __restrict__ hout,           // [N][D] bf16
    float* __restrict__ pooled /* [G][D] this layer */) {
    __shared__ ushort Wf1[4096];                        // 8 KB frag-linear bf16 (bn-folded)
    __shared__ ushort Wf2[4096];                        // 8 KB frag-linear bf16
    __shared__ __align__(16) ushort stage[4][3][1024];  // 24 KB: 3-slot ring/wave
    __shared__ __align__(16) ushort zbufs[4][512];      // 4 KB: z rows 0-7/wave (swizzled)
    __shared__ __align__(16) unsigned pbuf[4][512];     // 8 KB: perm segment/wave
    // (zbufs A-frag reads for pad rows 8-15 overrun into pbuf: garbage, discarded)

    const float inv_std = rsqrtf(1.0f + BN_EPS);
    const int tid = threadIdx.x;
    // Build B-fragments: frag = nt*2+kh; elem (l,j) = W[kh*32+(l>>4)*8+j][nt*16+(l&15)]
    for (int idx = tid; idx < 4096; idx += 256) {
        int frag = idx >> 9;
        int l = (idx >> 3) & 63;
        int j = idx & 7;
        int kh = frag & 1, nt = frag >> 1;
        int k = kh * 32 + ((l >> 4) << 3) + j;
        int c = nt * 16 + (l & 15);
        Wf1[idx] = f2bf(W1[k * 64 + c] * (bng[c] * inv_std));
        Wf2[idx] = f2bf(W2[k * 64 + c]);
    }
    __syncthreads();

    const int lane = tid & 63;
    const int q = lane & 15;
    const int grp = lane >> 4;
    const int wid = tid >> 6;
    const int wv = blockIdx.x * 4 + wid;
    const int r0 = wv * RPW;          // N = 12500*8 exactly
    if (r0 >= N_NODES) return;

    int rpv = 0;
    if (lane < 9) rpv = row_ptr[r0 + lane];
    int cval = __shfl(rpv, lane + 1) - rpv;    // degree, valid lane<8
    int bval = 0;
    if (lane < RPW) bval = batch[r0 + lane];
    const int segbase = __shfl(rpv, 0);
    const int seglen  = __shfl(rpv, 8) - segbase;

    const float ev = 1.0f + eps[layer];
    const float QDEC = 4.8828125e-4f;  // 1/2048
    float w4[4], b4[4];
    {
        float4 t = ((const float4*)edgeW)[q];
        w4[0] = t.x; w4[1] = t.y; w4[2] = t.z; w4[3] = t.w;
        float4 u = ((const float4*)edgeB)[q];
        b4[0] = u.x; b4[1] = u.y; b4[2] = u.z; b4[3] = u.w;
    }
    // per-lane epilogue biases indexed by output col = nt*16 + (lane&15)
    float blv1n[4], blv2n[4];
    #pragma unroll
    for (int nt = 0; nt < 4; ++nt) {
        int c = nt * 16 + (lane & 15);
        blv1n[nt] = fmaf(b1[c], bng[c] * inv_std, bnb[c]);
        blv2n[nt] = b2[c];
    }
    const ushort4* h4 = (const ushort4*)hbf;

    // z-row sink: pack bf16, store swizzled into zbufs (grp0 lanes only)
    auto store_z = [&](int ai, float z0, float z1, float z2, float z3) {
        if (grp == 0) {
            unsigned lo = (unsigned)f2bf(z0) | ((unsigned)f2bf(z1) << 16);
            unsigned hi = (unsigned)f2bf(z2) | ((unsigned)f2bf(z3) << 16);
            int ad = (ai * 128 + q * 8) ^ ((ai & 7) << 4);
            *(uint2*)((char*)&zbufs[wid][0] + ad) = make_uint2(lo, hi);
        }
    };

    if (seglen <= 512) {
        // ---- fast path: perm segment in LDS, depth-2 async gather ----
        if (seglen > 0) {
            gload_lds16(perm + segbase + lane * 4, &pbuf[wid][0]);
            if (seglen > 256)
                gload_lds16(perm + segbase + 256 + lane * 4, &pbuf[wid][256]);
        }
        asm volatile("s_waitcnt vmcnt(0)" ::: "memory");  // pbuf ready

        auto nchunks = [&](int i) { return (__shfl(cval, i) + 15) >> 4; };
        int nTot = 0;
        #pragma unroll
        for (int i = 0; i < RPW; ++i) nTot += nchunks(i);

        int i_iss = 0, c_iss = 0;
        while (i_iss < RPW && nchunks(i_iss) == 0) ++i_iss;
        auto issue1 = [&](int slot) {
            int rb = __shfl(rpv, i_iss) - segbase;
            int so = rb + (c_iss << 4);
            ushort* sb = &stage[wid][slot][0];
            int eloc = lane >> 3, sub = lane & 7;
            #pragma unroll
            for (int j = 0; j < 2; ++j) {
                int idx = min(so + (j << 3) + eloc, 511);
                unsigned pe = pbuf[wid][idx];
                gload_lds16(hbf + (size_t)(pe >> 15) * D + sub * 8, sb + j * 512);
            }
            ++c_iss;
            while (i_iss < RPW) {
                if (c_iss < nchunks(i_iss)) break;
                ++i_iss; c_iss = 0;
            }
        };
        auto accumulate = [&](const ushort* sb, int rb, int ebase, int cr, float* agg) {
            #pragma unroll
            for (int k = 0; k < 4; ++k) {
                int eidx = (k << 2) | grp;
                int idx = min(rb + ebase + eidx, 511);
                unsigned pe = pbuf[wid][idx];
                float m = (ebase + eidx < cr) ? 1.0f : 0.0f;
                float a = fmaf((float)(pe & 0x7FFFu), QDEC, -8.0f);
                ushort4 hv = *(const ushort4*)(sb + (eidx << 6) + (q << 2));
                agg[0] = fmaf(m, fmaxf(fmaf(a, w4[0], b4[0]) + bf2f(hv.x), 0.f), agg[0]);
                agg[1] = fmaf(m, fmaxf(fmaf(a, w4[1], b4[1]) + bf2f(hv.y), 0.f), agg[1]);
                agg[2] = fmaf(m, fmaxf(fmaf(a, w4[2], b4[2]) + bf2f(hv.z), 0.f), agg[2]);
                agg[3] = fmaf(m, fmaxf(fmaf(a, w4[3], b4[3]) + bf2f(hv.w), 0.f), agg[3]);
            }
        };

        int nIss = 0, sIss = 0, nCon = 0, sCon = 0;
        if (nIss < nTot) { issue1(sIss); sIss = 1; ++nIss; }
        if (nIss < nTot) { issue1(sIss); sIss = 2; ++nIss; }

        for (int ai = 0; ai < RPW; ++ai) {
            int cr = __shfl(cval, ai);
            int nch = (cr + 15) >> 4;
            int rb = __shfl(rpv, ai) - segbase;
            ushort4 hs4 = h4[(size_t)(r0 + ai) * 16 + q];   // self row
            float agg[4] = {0.f, 0.f, 0.f, 0.f};
            for (int ac = 0; ac < nch; ++ac) {
                if (nIss < nTot) {
                    issue1(sIss);
                    sIss = (sIss == 2) ? 0 : sIss + 1;
                    ++nIss;
                    asm volatile("s_waitcnt vmcnt(4)" ::: "memory");
                } else if (nIss - nCon == 2) {
                    asm volatile("s_waitcnt vmcnt(2)" ::: "memory");
                } else {
                    asm volatile("s_waitcnt vmcnt(0)" ::: "memory");
                }
                accumulate(&stage[wid][sCon][0], rb, ac << 4, cr, agg);
                sCon = (sCon == 2) ? 0 : sCon + 1;
                ++nCon;
            }
            #pragma unroll
            for (int c = 0; c < 4; ++c) {
                agg[c] += __shfl_xor(agg[c], 16);
                agg[c] += __shfl_xor(agg[c], 32);
            }
            store_z(ai,
                    fmaf(ev, bf2f(hs4.x), agg[0]), fmaf(ev, bf2f(hs4.y), agg[1]),
                    fmaf(ev, bf2f(hs4.z), agg[2]), fmaf(ev, bf2f(hs4.w), agg[3]));
        }
    } else {
        // ---- rare fallback: serial direct gather (no staging) ----
        for (int ai = 0; ai < RPW; ++ai) {
            int cr = __shfl(cval, ai);
            int rbg = __shfl(rpv, ai);
            ushort4 hs4 = h4[(size_t)(r0 + ai) * 16 + q];
            float agg[4] = {0.f, 0.f, 0.f, 0.f};
            for (int k = grp; k < cr; k += 4) {
                unsigned pe = perm[rbg + k];
                float a = fmaf((float)(pe & 0x7FFFu), QDEC, -8.0f);
                ushort4 hv = h4[(size_t)(pe >> 15) * 16 + q];
                agg[0] += fmaxf(fmaf(a, w4[0], b4[0]) + bf2f(hv.x), 0.f);
                agg[1] += fmaxf(fmaf(a, w4[1], b4[1]) + bf2f(hv.y), 0.f);
                agg[2] += fmaxf(fmaf(a, w4[2], b4[2]) + bf2f(hv.z), 0.f);
                agg[3] += fmaxf(fmaf(a, w4[3], b4[3]) + bf2f(hv.w), 0.f);
            }
            #pragma unroll
            for (int c = 0; c < 4; ++c) {
                agg[c] += __shfl_xor(agg[c], 16);
                agg[c] += __shfl_xor(agg[c], 32);
            }
            store_z(ai,
                    fmaf(ev, bf2f(hs4.x), agg[0]), fmaf(ev, bf2f(hs4.y), agg[1]),
                    fmaf(ev, bf2f(hs4.z), agg[2]), fmaf(ev, bf2f(hs4.w), agg[3]));
        }
    }

    // ---- MFMA GEMM phase (per wave; all gathers drained, slots idle) --------
    // A layout: lane holds A[row=lane&15][k=kh*32+(lane>>4)*8+j]
    // C layout: lane holds C[row=(lane>>4)*4+i][col=nt*16+(lane&15)]
    const int arow = lane & 15, agrp = lane >> 4;
    ushort* yb = &stage[wid][0][0];           // y1 bounce buffer (slot 0)
    v8s a1[2];
    #pragma unroll
    for (int kh = 0; kh < 2; ++kh) {
        int ad = (arow * 128 + kh * 64 + agrp * 16) ^ ((arow & 7) << 4);
        a1[kh] = *(const v8s*)((char*)&zbufs[wid][0] + ad);
    }
    #pragma unroll
    for (int nt = 0; nt < 4; ++nt) {
        v4f acc = {0.f, 0.f, 0.f, 0.f};
        acc = __builtin_amdgcn_mfma_f32_16x16x32_bf16(
            a1[0], *(const v8s*)&Wf1[(nt * 2 + 0) * 512 + lane * 8], acc, 0, 0, 0);
        acc = __builtin_amdgcn_mfma_f32_16x16x32_bf16(
            a1[1], *(const v8s*)&Wf1[(nt * 2 + 1) * 512 + lane * 8], acc, 0, 0, 0);
        #pragma unroll
        for (int i = 0; i < 4; ++i) {
            float y = fmaxf(acc[i] + blv1n[nt], 0.f);
            int row = agrp * 4 + i;
            int ad = (row * 128 + (nt * 16 + arow) * 2) ^ ((row & 7) << 4);
            *(ushort*)((char*)yb + ad) = f2bf(y);
        }
    }
    v8s a2[2];
    #pragma unroll
    for (int kh = 0; kh < 2; ++kh) {
        int ad = (arow * 128 + kh * 64 + agrp * 16) ^ ((arow & 7) << 4);
        a2[kh] = *(const v8s*)((char*)yb + ad);
    }
    float y2v[16];   // [nt*4+i], static-indexed
    #pragma unroll
    for (int nt = 0; nt < 4; ++nt) {
        v4f acc = {0.f, 0.f, 0.f, 0.f};
        acc = __builtin_amdgcn_mfma_f32_16x16x32_bf16(
            a2[0], *(const v8s*)&Wf2[(nt * 2 + 0) * 512 + lane * 8], acc, 0, 0, 0);
        acc = __builtin_amdgcn_mfma_f32_16x16x32_bf16(
            a2[1], *(const v8s*)&Wf2[(nt * 2 + 1) * 512 + lane * 8], acc, 0, 0, 0);
        #pragma unroll
        for (int i = 0; i < 4; ++i)
            y2v[nt * 4 + i] = fmaxf(acc[i] + blv2n[nt], 0.f);
    }
    // output rows 0-7 (lanes agrp<2 hold real rows); rows 8-15 are pad garbage
    if (agrp < 2) {
        #pragma unroll
        for (int i = 0; i < 4; ++i) {
            int row = agrp * 4 + i;
            #pragma unroll
            for (int nt = 0; nt < 4; ++nt)
                hout[(size_t)(r0 + row) * D + nt * 16 + arow] =
                    (ushort)f2bf(y2v[nt * 4 + i]);
        }
    }
    // pooling: fast path when all 8 rows share one graph (sorted batch)
    int g0 = __shfl(bval, 0), g7 = __shfl(bval, 7);
    if (g0 == g7) {
        #pragma unroll
        for (int nt = 0; nt < 4; ++nt) {
            float m = fmaxf(fmaxf(y2v[nt * 4 + 0], y2v[nt * 4 + 1]),
                            fmaxf(y2v[nt * 4 + 2], y2v[nt * 4 + 3]));
            m = fmaxf(m, __shfl_xor(m, 16));   // combine rows 0-3 with 4-7
            if (lane < 16)
                atomicMax((unsigned*)&pooled[g0 * D + nt * 16 + lane],
                          __float_as_uint(m));
        }
    } else {
        if (agrp < 2) {
            #pragma unroll
            for (int i = 0; i < 4; ++i) {
                int g = __shfl(bval, agrp * 4 + i);
                #pragma unroll
                for (int nt = 0; nt < 4; ++nt)
                    atomicMax((unsigned*)&pooled[g * D + nt * 16 + arow],
                              __float_as_uint(y2v[nt * 4 + i]));
            }
        }
    }
}

// ---------------- MLP head ---------------------------------------------------
__global__ __launch_bounds__(256) void mlp_kernel(
    const float* __restrict__ pooled,  // [5][G][D]
    const float* __restrict__ l1W, const float* __restrict__ l1b,
    const float* __restrict__ l2W, const float* __restrict__ l2b,
    float* __restrict__ out) {
    __shared__ float gl[5 * D];
    __shared__ float tl[4 * D];
    int gid = blockIdx.x;
    int tid = threadIdx.x;
    for (int idx = tid; idx < 5 * D; idx += 256) {
        int k = idx >> 6;
        int d = idx & 63;
        gl[idx] = pooled[k * (G_GRAPHS * D) + gid * D + d];
    }
    __syncthreads();
    {
        float acc = l1b[tid];
        for (int m = 0; m < 5 * D; ++m)
            acc = fmaf(gl[m], l1W[m * 256 + tid], acc);
        tl[tid] = fmaxf(acc, 0.0f);
    }
    __syncthreads();
    if (tid < 5) {
        float acc = l2b[tid];
        for (int m = 0; m < 4 * D; ++m)
            acc = fmaf(tl[m], l2W[m * 5 + tid], acc);
        out[gid * 5 + tid] = acc;
    }
}

extern "C" void kernel_launch(void* const* d_in, const int* in_sizes, int n_in,
                              void* d_out, int out_size, void* d_ws, size_t ws_size,
                              hipStream_t stream) {
    const float* x     = (const float*)d_in[0];
    const int*   ei    = (const int*)d_in[1];
    const float* ea    = (const float*)d_in[2];
    const int*   batch = (const int*)d_in[3];
    const float* eps   = (const float*)d_in[4];
    const float* edgeW = (const float*)d_in[5];
    const float* edgeB = (const float*)d_in[6];
    const float* W1    = (const float*)d_in[7];
    const float* b1    = (const float*)d_in[8];
    const float* bng   = (const float*)d_in[9];
    const float* bnb   = (const float*)d_in[10];
    const float* W2    = (const float*)d_in[11];
    const float* b2    = (const float*)d_in[12];
    const float* l1W   = (const float*)d_in[13];
    const float* l1b   = (const float*)d_in[14];
    const float* l2W   = (const float*)d_in[15];
    const float* l2b   = (const float*)d_in[16];
    float* out = (float*)d_out;

    char* ws = (char*)d_ws;
    size_t nbf = (size_t)N_NODES * D * sizeof(ushort);  // 12.8 MB
    size_t off = 0;
    ushort* hbfA  = (ushort*)(ws + off); off += nbf;
    ushort* hbfB  = (ushort*)(ws + off); off += nbf;
    float* pooled = (float*)(ws + off);  off += (size_t)L_LAYERS * G_GRAPHS * D * sizeof(float);
    off = (off + 15) & ~(size_t)15;
    unsigned* perm = (unsigned*)(ws + off); off += (size_t)N_EDGES * sizeof(unsigned); // 12.8 MB
    int* row_ptr  = (int*)(ws + off);    off += (size_t)(N_NODES + 1) * sizeof(int);
    int* gcount   = (int*)(ws + off);    off += (size_t)TOTC * sizeof(int);   // 401 KB
    int* ofs      = (int*)(ws + off);    off += (size_t)TOTC * sizeof(int);   // 401 KB
    int* bucketbase = (int*)(ws + off);  off += (NBUCK + 4) * sizeof(int);
    int* bsum     = (int*)(ws + off);    off += 256 * sizeof(int);
    int* bbase    = (int*)(ws + off);    off += 256 * sizeof(int);
    off = (off + 15) & ~(size_t)15;
    uint2* inter  = (uint2*)(ws + off);  off += (size_t)N_EDGES * sizeof(uint2);  // 25.6 MB

    hipMemsetAsync(pooled, 0, (size_t)L_LAYERS * G_GRAPHS * D * sizeof(float), stream);

    xcvt_kernel<<<1024, 256, 0, stream>>>(x, hbfA);
    hist512_kernel<<<NPB, 256, 0, stream>>>(ei, gcount);
    scan_partial<<<256, 256, 0, stream>>>(gcount, bsum);
    scan_base<<<1, 256, 0, stream>>>(bsum, bbase, bucketbase);
    scan_apply<<<256, 256, 0, stream>>>(gcount, bbase, ofs, bucketbase);
    part_kernel<<<NPB, 256, 0, stream>>>(ei, ea, ofs, inter);
    bucket_kernel<<<NBUCK, 256, 0, stream>>>(inter, bucketbase, perm, row_ptr);

    const int waves  = (N_NODES + RPW - 1) / RPW;   // 12500
    const int blocks = (waves + 3) / 4;             // 3125

    const ushort* hcur = hbfA;
    for (int i = 0; i < L_LAYERS; ++i) {
        ushort* hnext = (i & 1) ? hbfA : hbfB;
        layer_kernel<<<blocks, 256, 0, stream>>>(
            hcur, row_ptr, perm, eps, i,
            edgeW + i * D, edgeB + i * D,
            W1 + i * D * D, b1 + i * D,
            bng + i * D, bnb + i * D,
            W2 + i * D * D, b2 + i * D,
            batch, hnext, pooled + i * G_GRAPHS * D);
        hcur = hnext;
    }
    mlp_kernel<<<G_GRAPHS, 256, 0, stream>>>(pooled, l1W, l1b, l2W, l2b, out);
}